// Round 12
// baseline (398.900 us; speedup 1.0000x reference)
//
#include <hip/hip_runtime.h>

// EMAttention2d on MI355X — v12: v11 with ONE change — stem reverted to the
// measured-faster split path: vectorized xpose (fp32->fp16 transpose, ~30us)
// + single-buffer 2-phase gemm_sb (77us, dual-layout epilogue).
// Everything else identical to v11 (dbuf EM kernels, de-atomic mu partials,
// BN stats fused into head). B=16, C=512, N=4096, K=64, 3 EM iters.
// mu_b = colnorm_c(yf^T @ z)  (zn normalization cancels under column L2 norm).

typedef _Float16 half_t;
typedef _Float16 half4 __attribute__((ext_vector_type(4)));
typedef _Float16 half8 __attribute__((ext_vector_type(8)));
typedef float f32x4 __attribute__((ext_vector_type(4)));

#define GLD_LDS(gp, lp) __builtin_amdgcn_global_load_lds( \
    (const __attribute__((address_space(1))) void*)(gp),  \
    (__attribute__((address_space(3))) void*)(lp), 16, 0, 0)

#define SBAR __builtin_amdgcn_sched_barrier(0)
#define RAWBAR do { SBAR; __builtin_amdgcn_s_barrier(); SBAR; } while (0)
#define LGKM0 do { asm volatile("s_waitcnt lgkmcnt(0)" ::: "memory"); SBAR; } while (0)

template <int L> __device__ __forceinline__ void vmwait() {
  if constexpr (L == 8) asm volatile("s_waitcnt vmcnt(8)" ::: "memory");
  else if constexpr (L == 6) asm volatile("s_waitcnt vmcnt(6)" ::: "memory");
  else if constexpr (L == 4) asm volatile("s_waitcnt vmcnt(4)" ::: "memory");
  else asm volatile("s_waitcnt vmcnt(0)" ::: "memory");
}

constexpr int CB = 16;       // batch
constexpr int CC = 512;      // channels
constexpr int CN = 4096;     // H*W
constexpr int CKK = 64;      // codebook size K
constexpr long MALL = (long)CB * CN;   // 65536

__device__ inline int swz8(int bid, int n) {   // bijective (n % 8 == 0)
  return (bid & 7) * (n >> 3) + (bid >> 3);
}

// ---------------------------------------------------------------------------
// K0: convert weights to fp16; init per-batch muT (K,C) and mu_ck (C,K).
__global__ __launch_bounds__(256) void prep(
    const float* __restrict__ stem_w, const float* __restrict__ head_w,
    const float* __restrict__ mu,
    half_t* __restrict__ swh, half_t* __restrict__ hwh,
    half_t* __restrict__ muT, half_t* __restrict__ muck)
{
  int i = blockIdx.x * 256 + threadIdx.x;   // grid covers C*C = 262144
  swh[i] = (half_t)stem_w[i];
  hwh[i] = (half_t)head_w[i];
  if (i < CC * CKK) {
    int c = i >> 6, k = i & 63;
    half_t v = (half_t)mu[i];               // mu is (C,K) row-major
    for (int b = 0; b < CB; ++b) {
      muT[(long)b * CKK * CC + (long)k * CC + c] = v;
      muck[(long)b * CC * CKK + i] = v;
    }
  }
}

// ---------------------------------------------------------------------------
// x (B,C,N) fp32 -> xT (B,N,C) fp16. Vectorized: float4 loads, half8 stores.
__global__ __launch_bounds__(256) void xpose(
    const float* __restrict__ in, half_t* __restrict__ outT)
{
  __shared__ half_t t[64][72];               // [c][n], pad 72
  const int n0 = blockIdx.x * 64, c0 = blockIdx.y * 64;
  const long bz = blockIdx.z;
  const float* ib = in + bz * (long)CC * CN;
  half_t* ob = outT + bz * (long)CC * CN;
  const int tid = threadIdx.x;
  {                                          // load 64c x 64n, float4-wide
    const int c = tid >> 2, l4 = tid & 3;
    const float* p = ib + (long)(c0 + c) * CN + n0;
#pragma unroll
    for (int e = 0; e < 4; ++e) {
      const int nq = (l4 + e * 4) * 4;
      f32x4 v = *(const f32x4*)&p[nq];
#pragma unroll
      for (int j = 0; j < 4; ++j) t[c][nq + j] = (half_t)v[j];
    }
  }
  __syncthreads();
#pragma unroll
  for (int e = 0; e < 2; ++e) {              // store half8-wide
    const int q = e * 256 + tid;             // 8 lanes cover one 128 B row
    const int n = q >> 3, c8 = (q & 7) * 8;
    half8 v;
#pragma unroll
    for (int j = 0; j < 8; ++j) v[j] = t[c8 + j][n];
    *(half8*)&ob[(long)(n0 + n) * CC + c0 + c8] = v;
  }
}

// ---------------------------------------------------------------------------
// Stem GEMM (single-buffer 2-phase, the measured 77us config): Yf (B*N, C)
// = xT @ Bw^T + bias, dual-layout epilogue also writing ycn (B,C,N).
// 128x128 tile, 33KB LDS -> 4 blocks/CU, swizzled staging, setprio.
__global__ __launch_bounds__(256) void gemm_sb(
    const half_t* __restrict__ A, const half_t* __restrict__ Bw,
    const float* __restrict__ bias,
    half_t* __restrict__ Co, half_t* __restrict__ CoT)
{
  constexpr int HB = 256 * 64;                 // halfs, single buffer
  constexpr int EPS = 128 * 132;
  constexpr int TOT = HB > EPS ? HB : EPS;
  __shared__ __align__(16) half_t smem[TOT];

  const int tid = threadIdx.x, wid = tid >> 6, lane = tid & 63;
  const int bid = swz8(blockIdx.x, gridDim.x);
  const int tm = bid >> 2, tn = bid & 3;       // 512 m-tiles x 4 n-tiles
  const half_t* Ab = A + (long)tm * 128 * CC;
  const half_t* Bb = Bw + (long)tn * 128 * CC;
  const int wr = wid >> 1, wc = wid & 1;

  const int r8 = lane >> 3;
  const int gcs = ((lane & 7) ^ r8) * 8;

  auto stage = [&](int ks) {
    half_t* dA = smem;
    half_t* dB = smem + 128 * 64;
    const half_t* ga = Ab + (long)ks * 64;
#pragma unroll
    for (int c = wid; c < 16; c += 4)
      GLD_LDS(ga + (long)(c * 8 + r8) * CC + gcs, &dA[c * 512]);
    const half_t* gb = Bb + (long)ks * 64;
#pragma unroll
    for (int c = wid; c < 16; c += 4)
      GLD_LDS(gb + (long)(c * 8 + r8) * CC + gcs, &dB[c * 512]);
  };

  f32x4 acc[4][4];
#pragma unroll
  for (int i = 0; i < 4; ++i)
#pragma unroll
    for (int j = 0; j < 4; ++j) acc[i][j] = f32x4{0.f, 0.f, 0.f, 0.f};

  for (int ks = 0; ks < 8; ++ks) {
    stage(ks);
    asm volatile("s_waitcnt vmcnt(0)" ::: "memory"); SBAR;
    RAWBAR;
    const half_t* lA = smem;
    const half_t* lB = smem + 128 * 64;
#pragma unroll
    for (int kk = 0; kk < 2; ++kk) {
      half8 af[4], bfr[4];
      const int cg = kk * 4 + (lane >> 4);
#pragma unroll
      for (int i = 0; i < 4; ++i) {
        const int rA = wr * 64 + i * 16 + (lane & 15);
        af[i] = *(const half8*)&lA[rA * 64 + ((cg ^ (rA & 7)) << 3)];
      }
#pragma unroll
      for (int j = 0; j < 4; ++j) {
        const int rB = wc * 64 + j * 16 + (lane & 15);
        bfr[j] = *(const half8*)&lB[rB * 64 + ((cg ^ (rB & 7)) << 3)];
      }
      __builtin_amdgcn_s_setprio(1);
#pragma unroll
      for (int i = 0; i < 4; ++i)
#pragma unroll
        for (int j = 0; j < 4; ++j)
          acc[i][j] = __builtin_amdgcn_mfma_f32_16x16x32_f16(af[i], bfr[j],
                                                             acc[i][j], 0, 0, 0);
      __builtin_amdgcn_s_setprio(0);
    }
    RAWBAR;
  }

  // Epilogue: ep[n-of-tile][m], pitch 132, dual-layout wide stores.
  constexpr int PIT = 132;
  half_t* ep = smem;
#pragma unroll
  for (int j = 0; j < 4; ++j) {
    const int nl = wc * 64 + j * 16 + (lane & 15);
    const float bv = bias[tn * 128 + nl];
#pragma unroll
    for (int i = 0; i < 4; ++i) {
      const int ml = wr * 64 + i * 16 + ((lane >> 4) << 2);
      half4 h;
#pragma unroll
      for (int r = 0; r < 4; ++r) h[r] = (half_t)(acc[i][j][r] + bv);
      *(half4*)&ep[nl * PIT + ml] = h;
    }
  }
  __syncthreads();
  const long row0 = (long)tm * 128;
  const long b = row0 >> 12;
  const int n0 = (int)(row0 & 4095);
  { // Yf row-major (m, o-contig)
#pragma unroll
    for (int s = 0; s < 8; ++s) {
      const int q = tid + 256 * s;
      const int m = q & 127, cc8 = q >> 7;
      half8 v;
#pragma unroll
      for (int e = 0; e < 8; ++e) v[e] = ep[(cc8 * 8 + e) * PIT + m];
      *(half8*)&Co[(row0 + m) * CC + tn * 128 + cc8 * 8] = v;
    }
  }
  { // ycn (B, o, 4096)
#pragma unroll
    for (int s = 0; s < 8; ++s) {
      const int q = tid + 256 * s;
      const int mc = q & 15, cl = q >> 4;
      half8 v = *(const half8*)&ep[cl * PIT + mc * 8];
      *(half8*)&CoT[(b * CC + tn * 128 + cl) * CN + n0 + mc * 8] = v;
    }
  }
}

// ---------------------------------------------------------------------------
// Generic fp16 GEMM, A@B^T form (v11 dbuf counted-vmcnt pipeline + swizzle).
// MODE bit0: +bias; bit1: relu; bit2: plain fp32 partial store into Cacc at
// split offset (blockIdx.y) — no atomics, regions disjoint.
// EPI bit0: LDS epilogue row-major. EPI bit1: transposed (B, Nn, 4096).
// STATS (requires EPI&2): fused per-channel sum/sumsq atomics into stats[].
template <int BM, int BN, int MODE, int EPI, bool SWZ, bool STATS>
__global__ __launch_bounds__(256) void gemm_abt(
    const half_t* __restrict__ A, const half_t* __restrict__ Bm,
    half_t* __restrict__ Co, half_t* __restrict__ CoT,
    float* __restrict__ Cacc, const float* __restrict__ bias,
    float* __restrict__ stats,
    int M, int Nn, int Kk, int ksplit, long sA, long sB, long sC)
{
  constexpr int FM = BM / 32, FN = BN / 32;
  constexpr int HB = (BM + BN) * 64;
  constexpr int LCNT = (BM / 8) / 4 + (BN / 8) / 4;
  constexpr int STG = 2 * HB;
  constexpr int EPS = (EPI != 0) ? BN * (BM + 4) : 0;
  constexpr int TOT = STG > EPS ? STG : EPS;
  __shared__ __align__(16) half_t smem[TOT];

  const int tid = threadIdx.x, wid = tid >> 6, lane = tid & 63;
  int bid = blockIdx.x;
  if constexpr (SWZ) bid = swz8(bid, gridDim.x);
  const int tilesN = Nn / BN;
  const int tm = bid / tilesN, tn = bid % tilesN;
  const long bz = blockIdx.z;
  const half_t* Ab = A + bz * sA + (long)tm * BM * Kk;
  const half_t* Bb = Bm + bz * sB + (long)tn * BN * Kk;
  const int ksteps = Kk >> 6;
  const int per = ksteps / ksplit;
  const int ks0 = blockIdx.y * per, ks1 = ks0 + per;
  const int wr = wid >> 1, wc = wid & 1;

  const int r8 = lane >> 3;
  const int gcs = ((lane & 7) ^ r8) * 8;

  auto stage = [&](int ks, int buf) {
    half_t* dA = smem + buf * HB;
    half_t* dB = dA + BM * 64;
    const half_t* ga = Ab + (long)ks * 64;
#pragma unroll
    for (int c = wid; c < BM / 8; c += 4)
      GLD_LDS(ga + (long)(c * 8 + r8) * Kk + gcs, &dA[c * 512]);
    const half_t* gb = Bb + (long)ks * 64;
#pragma unroll
    for (int c = wid; c < BN / 8; c += 4)
      GLD_LDS(gb + (long)(c * 8 + r8) * Kk + gcs, &dB[c * 512]);
  };

  f32x4 acc[FM][FN];
#pragma unroll
  for (int i = 0; i < FM; ++i)
#pragma unroll
    for (int j = 0; j < FN; ++j) acc[i][j] = f32x4{0.f, 0.f, 0.f, 0.f};

  stage(ks0, 0);
  if (ks0 + 1 < ks1) { stage(ks0 + 1, 1); vmwait<LCNT>(); }
  else               { vmwait<0>(); }
  RAWBAR;

  int cur = 0;
  for (int ks = ks0; ks < ks1; ++ks) {
    const half_t* lA = smem + cur * HB;
    const half_t* lB = lA + BM * 64;
#pragma unroll
    for (int kk = 0; kk < 2; ++kk) {
      half8 af[FM], bfr[FN];
      const int cg = kk * 4 + (lane >> 4);
#pragma unroll
      for (int i = 0; i < FM; ++i) {
        const int rA = wr * (BM / 2) + i * 16 + (lane & 15);
        af[i] = *(const half8*)&lA[rA * 64 + ((cg ^ (rA & 7)) << 3)];
      }
#pragma unroll
      for (int j = 0; j < FN; ++j) {
        const int rB = wc * (BN / 2) + j * 16 + (lane & 15);
        bfr[j] = *(const half8*)&lB[rB * 64 + ((cg ^ (rB & 7)) << 3)];
      }
      __builtin_amdgcn_s_setprio(1);
#pragma unroll
      for (int i = 0; i < FM; ++i)
#pragma unroll
        for (int j = 0; j < FN; ++j)
          acc[i][j] = __builtin_amdgcn_mfma_f32_16x16x32_f16(af[i], bfr[j],
                                                             acc[i][j], 0, 0, 0);
      __builtin_amdgcn_s_setprio(0);
    }
    RAWBAR;
    const bool more = (ks + 2 < ks1);
    if (more) { stage(ks + 2, cur); vmwait<LCNT>(); }
    else      { vmwait<0>(); }
    RAWBAR;
    cur ^= 1;
  }

  if constexpr (EPI != 0) {
    static_assert(BM == 128 && BN == 128, "LDS epilogue assumes 128x128");
    constexpr int PIT = BM + 4;
    half_t* ep = smem;
#pragma unroll
    for (int j = 0; j < FN; ++j) {
      const int nl = wc * 64 + j * 16 + (lane & 15);
      float bv = 0.f;
      if constexpr (MODE & 1) bv = bias[tn * BN + nl];
      float s1 = 0.f, s2 = 0.f;
#pragma unroll
      for (int i = 0; i < FM; ++i) {
        const int ml = wr * 64 + i * 16 + ((lane >> 4) << 2);
        half4 h;
#pragma unroll
        for (int r = 0; r < 4; ++r) {
          float v = acc[i][j][r] + bv;
          if constexpr (MODE & 2) v = fmaxf(v, 0.f);
          if constexpr (STATS) { s1 += v; s2 += v * v; }
          h[r] = (half_t)v;
        }
        *(half4*)&ep[nl * PIT + ml] = h;
      }
      if constexpr (STATS) {     // reduce 64 m-rows this wave holds (col nl)
        s1 += __shfl_xor(s1, 16); s1 += __shfl_xor(s1, 32);
        s2 += __shfl_xor(s2, 16); s2 += __shfl_xor(s2, 32);
        if (lane < 16) {
          const int ch = tn * BN + nl;
          atomicAdd(&stats[ch], s1);
          atomicAdd(&stats[CC + ch], s2);
        }
      }
    }
    __syncthreads();
    const long rowbase = (long)tm * BM;
    if constexpr (EPI & 1) {
#pragma unroll
      for (int s = 0; s < 8; ++s) {
        const int q = tid + 256 * s;
        const int m = q & 127, cc8 = q >> 7;
        half8 v;
#pragma unroll
        for (int e = 0; e < 8; ++e) v[e] = ep[(cc8 * 8 + e) * PIT + m];
        *(half8*)&Co[bz * sC + (rowbase + m) * Nn + tn * BN + cc8 * 8] = v;
      }
    }
    if constexpr (EPI & 2) {
      const long b = rowbase >> 12, nbase = rowbase & 4095;
#pragma unroll
      for (int s = 0; s < 8; ++s) {
        const int q = tid + 256 * s;
        const int mc = q & 15, cl = q >> 4;
        half8 v = *(const half8*)&ep[cl * PIT + mc * 8];
        *(half8*)&CoT[(b * Nn + tn * BN + cl) * 4096 + nbase + mc * 8] = v;
      }
    }
  } else {
#pragma unroll
    for (int j = 0; j < FN; ++j) {
      const int n = tn * BN + wc * (BN / 2) + j * 16 + (lane & 15);
      float bv = 0.f;
      if constexpr (MODE & 1) bv = bias[n];
#pragma unroll
      for (int i = 0; i < FM; ++i) {
        const int mbase = tm * BM + wr * (BM / 2) + i * 16 + ((lane >> 4) << 2);
#pragma unroll
        for (int r = 0; r < 4; ++r) {
          if constexpr ((MODE & 4) != 0) {   // per-split plain partial store
            const long idx = bz * sC + (long)blockIdx.y * ((long)BM * Nn) +
                             (long)(mbase + r) * Nn + n;
            Cacc[idx] = acc[i][j][r];
          } else {
            const long idx = bz * sC + (long)(mbase + r) * Nn + n;
            float v = acc[i][j][r] + bv;
            if constexpr ((MODE & 2) != 0) v = fmaxf(v, 0.f);
            Co[idx] = (half_t)v;
          }
        }
      }
    }
  }
}

// ---------------------------------------------------------------------------
// K3 (v11 verbatim): S = Yf @ muT^T, in-register rowwise softmax, writes zT
// always, z when zp != nullptr (final iter). Dbuf counted-vmcnt staging.
__global__ __launch_bounds__(256) void s_softmax(
    const half_t* __restrict__ Yf, const half_t* __restrict__ muT,
    half_t* __restrict__ zp, half_t* __restrict__ zT)
{
  constexpr int HB = (128 + 64) * 64;     // halfs per staging buffer
  __shared__ __align__(16) union {
    half_t st[2 * HB];                    // 48 KiB staging (dbuf)
    half_t zh[128 * 68];                  // epilogue z tile
  } sm;
  const int tid = threadIdx.x, wid = tid >> 6, lane = tid & 63;
  const int tm = blockIdx.x;
  const long bz = blockIdx.z;
  const half_t* Ab = Yf + bz * (long)CN * CC + (long)tm * 128 * CC;
  const half_t* Bb = muT + bz * (long)CKK * CC;

  const int r8 = lane >> 3;
  const int gcs = ((lane & 7) ^ r8) * 8;

  auto stage = [&](int ks, int buf) {
    half_t* dA = sm.st + buf * HB;
    half_t* dB = dA + 128 * 64;
    const half_t* ga = Ab + (long)ks * 64;
#pragma unroll
    for (int c = wid; c < 16; c += 4)
      GLD_LDS(ga + (long)(c * 8 + r8) * CC + gcs, &dA[c * 512]);
    const half_t* gb = Bb + (long)ks * 64;
#pragma unroll
    for (int c = wid; c < 8; c += 4)
      GLD_LDS(gb + (long)(c * 8 + r8) * CC + gcs, &dB[c * 512]);
  };

  f32x4 acc[2][4];
#pragma unroll
  for (int i = 0; i < 2; ++i)
#pragma unroll
    for (int j = 0; j < 4; ++j) acc[i][j] = f32x4{0.f, 0.f, 0.f, 0.f};

  stage(0, 0);
  stage(1, 1);
  vmwait<6>();
  RAWBAR;
  int cur = 0;
  for (int ks = 0; ks < 8; ++ks) {   // Kk = 512
    const half_t* lA = sm.st + cur * HB;
    const half_t* lB = lA + 128 * 64;
#pragma unroll
    for (int kk = 0; kk < 2; ++kk) {
      half8 af[2], bfr[4];
      const int cg = kk * 4 + (lane >> 4);
#pragma unroll
      for (int i = 0; i < 2; ++i) {
        const int rA = wid * 32 + i * 16 + (lane & 15);
        af[i] = *(const half8*)&lA[rA * 64 + ((cg ^ (rA & 7)) << 3)];
      }
#pragma unroll
      for (int j = 0; j < 4; ++j) {
        const int rB = j * 16 + (lane & 15);
        bfr[j] = *(const half8*)&lB[rB * 64 + ((cg ^ (rB & 7)) << 3)];
      }
      __builtin_amdgcn_s_setprio(1);
#pragma unroll
      for (int i = 0; i < 2; ++i)
#pragma unroll
        for (int j = 0; j < 4; ++j)
          acc[i][j] = __builtin_amdgcn_mfma_f32_16x16x32_f16(af[i], bfr[j],
                                                             acc[i][j], 0, 0, 0);
      __builtin_amdgcn_s_setprio(0);
    }
    RAWBAR;
    const bool more = (ks + 2 < 8);
    if (more) { stage(ks + 2, cur); vmwait<6>(); }
    else      { vmwait<0>(); }
    RAWBAR;
    cur ^= 1;
  }

  // In-register softmax over 64 cols per row.
#pragma unroll
  for (int i = 0; i < 2; ++i)
#pragma unroll
    for (int r = 0; r < 4; ++r) {
      float mx = fmaxf(fmaxf(acc[i][0][r], acc[i][1][r]),
                       fmaxf(acc[i][2][r], acc[i][3][r]));
#pragma unroll
      for (int m = 1; m < 16; m <<= 1) mx = fmaxf(mx, __shfl_xor(mx, m));
      float p[4], s = 0.f;
#pragma unroll
      for (int j = 0; j < 4; ++j) { p[j] = __expf(acc[i][j][r] - mx); s += p[j]; }
#pragma unroll
      for (int m = 1; m < 16; m <<= 1) s += __shfl_xor(s, m);
      const float inv = 1.f / s;
#pragma unroll
      for (int j = 0; j < 4; ++j) acc[i][j][r] = p[j] * inv;
    }

#pragma unroll
  for (int i = 0; i < 2; ++i)
#pragma unroll
    for (int j = 0; j < 4; ++j)
#pragma unroll
      for (int r = 0; r < 4; ++r) {
        const int row = wid * 32 + i * 16 + ((lane >> 4) << 2) + r;
        const int col = j * 16 + (lane & 15);
        sm.zh[row * 68 + col] = (half_t)acc[i][j][r];
      }
  __syncthreads();
  if (zp) { // z (N,K): rows n, contiguous k  (final iter only)
    const int nl = tid >> 1, seg = tid & 1;
    const long base = bz * (long)CN * CKK + (long)(tm * 128 + nl) * CKK + seg * 32;
#pragma unroll
    for (int g = 0; g < 4; ++g) {
      half8 v;
#pragma unroll
      for (int e = 0; e < 8; ++e) v[e] = sm.zh[nl * 68 + seg * 32 + g * 8 + e];
      *(half8*)&zp[base + g * 8] = v;
    }
  }
  { // zT (K,N): rows k, contiguous n
    const int k = tid >> 2, seg = tid & 3;
    const long base = bz * (long)CKK * CN + (long)k * CN + tm * 128 + seg * 32;
#pragma unroll
    for (int g = 0; g < 4; ++g) {
      half8 v;
#pragma unroll
      for (int e = 0; e < 8; ++e) v[e] = sm.zh[(seg * 32 + g * 8 + e) * 68 + k];
      *(half8*)&zT[base + g * 8] = v;
    }
  }
}

// ---------------------------------------------------------------------------
// mu = R / max(||R||_c, 1e-12) per (b,k), R = sum of 4 split partials.
// Writes muT (K,C) and mu_ck (C,K).
__global__ __launch_bounds__(64) void mu_norm(
    const float* __restrict__ acc, half_t* __restrict__ muT, half_t* __restrict__ muck)
{
  const int bk = blockIdx.x;           // b*64 + k
  const int b = bk >> 6, k = bk & 63;
  const float* base = acc + ((long)b * 4 * CKK + k) * CC;   // split stride K*C
  const int t = threadIdx.x;
  float v[8]; float s = 0.f;
#pragma unroll
  for (int e = 0; e < 8; ++e) {
    float a = base[t * 8 + e] + base[CKK * CC + t * 8 + e] +
              base[2 * CKK * CC + t * 8 + e] + base[3 * CKK * CC + t * 8 + e];
    v[e] = a; s += a * a;
  }
#pragma unroll
  for (int m = 1; m < 64; m <<= 1) s += __shfl_xor(s, m);
  const float inv = 1.f / fmaxf(sqrtf(s), 1e-12f);
  half8 o;
#pragma unroll
  for (int e = 0; e < 8; ++e) o[e] = (half_t)(v[e] * inv);
  *(half8*)&muT[(long)bk * CC + t * 8] = o;
  half_t* mc = muck + (long)b * CC * CKK;
#pragma unroll
  for (int e = 0; e < 8; ++e) mc[(long)(t * 8 + e) * CKK + k] = o[e];
}

// ---------------------------------------------------------------------------
__global__ void bn_param(const float* __restrict__ stats,
                         const float* __restrict__ gamma, const float* __restrict__ beta,
                         float* __restrict__ scsh)
{
  const int c = threadIdx.x;
  const float cnt = 1.f / 65536.f;
  const float mean = stats[c] * cnt;
  const float var = stats[CC + c] * cnt - mean * mean;
  const float sc = gamma[c] * rsqrtf(var + 1e-5f);
  scsh[c] = sc;
  scsh[CC + c] = beta[c] - mean * sc;
}

// ---------------------------------------------------------------------------
// out(B,C,N) = relu( hcn*sc + sh + x ), pure elementwise (hcn already (C,N)).
__global__ __launch_bounds__(256) void bn_final2(
    const half_t* __restrict__ hcn, const float* __restrict__ x,
    const float* __restrict__ scsh, float* __restrict__ out)
{
  const long i8 = (long)blockIdx.x * 256 + threadIdx.x;   // 8-elem chunk id
  const int c = (int)((i8 >> 9) & 511);
  const float sc = scsh[c], sh = scsh[CC + c];
  half8 h = *(const half8*)&hcn[i8 * 8];
  f32x4 x0 = *(const f32x4*)&x[i8 * 8];
  f32x4 x1 = *(const f32x4*)&x[i8 * 8 + 4];
  f32x4 o0, o1;
#pragma unroll
  for (int e = 0; e < 4; ++e) o0[e] = fmaxf((float)h[e] * sc + sh + x0[e], 0.f);
#pragma unroll
  for (int e = 0; e < 4; ++e) o1[e] = fmaxf((float)h[4 + e] * sc + sh + x1[e], 0.f);
  *(f32x4*)&out[i8 * 8] = o0;
  *(f32x4*)&out[i8 * 8 + 4] = o1;
}

// ---------------------------------------------------------------------------
extern "C" void kernel_launch(void* const* d_in, const int* in_sizes, int n_in,
                              void* d_out, int out_size, void* d_ws, size_t ws_size,
                              hipStream_t stream)
{
  const float* x      = (const float*)d_in[0];
  const float* mu     = (const float*)d_in[1];
  const float* stem_w = (const float*)d_in[2];
  const float* stem_b = (const float*)d_in[3];
  const float* head_w = (const float*)d_in[4];
  const float* head_b = (const float*)d_in[5];
  const float* bn_g   = (const float*)d_in[6];
  const float* bn_b   = (const float*)d_in[7];
  float* out = (float*)d_out;

  const size_t NEED = 214ull << 20;
  if (ws_size < NEED) {
    hipMemsetAsync(d_out, 0, (size_t)out_size * 4, stream);
    return;
  }
  char* ws = (char*)d_ws;
  const long MB = 1 << 20;
  half_t* xT   = (half_t*)(ws);              // 64 MiB; xT -> muacc -> y2f
  float* muacc = (float*)(ws);               //   8 MiB (b,4,K,C) fp32 partials
  half_t* y2f  = (half_t*)(ws);
  half_t* Yf   = (half_t*)(ws + 64 * MB);    // 64 MiB ; reused as hcn
  half_t* ycn  = (half_t*)(ws + 128 * MB);   // 64 MiB
  half_t* z    = (half_t*)(ws + 192 * MB);   // 8 MiB
  half_t* zT   = (half_t*)(ws + 200 * MB);   // 8 MiB
  half_t* muT  = (half_t*)(ws + 208 * MB);   // 1 MiB
  half_t* muck = (half_t*)(ws + 209 * MB);   // 1 MiB
  half_t* swh  = (half_t*)(ws + 212 * MB);
  half_t* hwh  = (half_t*)(ws + 212 * MB + 512 * 1024);
  float* stats = (float*)(ws + 213 * MB);
  float* scsh  = (float*)(ws + 213 * MB + 8 * 1024);
  half_t* hcn = Yf;    // Yf dead after final softmax

  prep<<<1024, 256, 0, stream>>>(stem_w, head_w, mu, swh, hwh, muT, muck);
  // xT (B,N,C) <- x (B,C,N)   (xT slot dead after stem; muacc/y2f reuse it)
  xpose<<<dim3(64, 8, 16), 256, 0, stream>>>(x, xT);
  // stem: Yf (B*N,C) + ycn (B,C,N) = xT @ stem_w^T + stem_b
  gemm_sb<<<2048, 256, 0, stream>>>(xT, swh, stem_b, Yf, ycn);

  for (int it = 0; it < 3; ++it) {
    s_softmax<<<dim3(32, 1, 16), 256, 0, stream>>>(
        Yf, muT, (it == 2) ? z : nullptr, zT);
    // mu partials (K,C) per split = zT @ ycn^T (4 splits, plain stores)
    gemm_abt<64, 128, 4, 0, false, false><<<dim3(4, 4, 16), 256, 0, stream>>>(
        zT, ycn, nullptr, nullptr, muacc, nullptr, nullptr, CKK, CC, CN, 4,
        (long)CKK * CN, (long)CC * CN, (long)4 * CKK * CC);
    mu_norm<<<CB * CKK, 64, 0, stream>>>(muacc, muT, muck);
  }
  // y2f (B,N,C) = relu(z @ mu_ck^T)
  gemm_abt<128, 128, 2, 1, true, false><<<dim3(128, 1, 16), 256, 0, stream>>>(
      z, muck, y2f, nullptr, nullptr, nullptr, nullptr, CN, CC, CKK, 1,
      (long)CN * CKK, (long)CC * CKK, (long)CN * CC);
  // head: hcn (B,C,N) = (y2f @ head_w^T + head_b), BN stats fused in epilogue
  hipMemsetAsync(stats, 0, 2 * CC * sizeof(float), stream);
  gemm_abt<128, 128, 1, 2, true, true><<<dim3(2048, 1, 1), 256, 0, stream>>>(
      y2f, hwh, nullptr, hcn, nullptr, head_b, stats, (int)MALL, CC, CC, 1, 0, 0, 0);

  bn_param<<<1, 512, 0, stream>>>(stats, bn_g, bn_b, scsh);
  bn_final2<<<16384, 256, 0, stream>>>(hcn, x, scsh, out);
}

// Round 13
// 398.067 us; speedup vs baseline: 1.0021x; 1.0021x over previous
//
#include <hip/hip_runtime.h>

// EMAttention2d on MI355X — v13: v11 with ONE change — stem split into the
// SCALAR xpose (256B/instr coalesced fp32 loads, ~30us) + single-buffer
// 2-phase gemm_sb (77us, dual-layout epilogue). v12's regression was its
// "vectorized" xpose (fragmented 64B bursts), not the split itself.
// Everything else identical to v11. B=16, C=512, N=4096, K=64, 3 EM iters.
// mu_b = colnorm_c(yf^T @ z)  (zn normalization cancels under column L2 norm).

typedef _Float16 half_t;
typedef _Float16 half4 __attribute__((ext_vector_type(4)));
typedef _Float16 half8 __attribute__((ext_vector_type(8)));
typedef float f32x4 __attribute__((ext_vector_type(4)));

#define GLD_LDS(gp, lp) __builtin_amdgcn_global_load_lds( \
    (const __attribute__((address_space(1))) void*)(gp),  \
    (__attribute__((address_space(3))) void*)(lp), 16, 0, 0)

#define SBAR __builtin_amdgcn_sched_barrier(0)
#define RAWBAR do { SBAR; __builtin_amdgcn_s_barrier(); SBAR; } while (0)

template <int L> __device__ __forceinline__ void vmwait() {
  if constexpr (L == 8) asm volatile("s_waitcnt vmcnt(8)" ::: "memory");
  else if constexpr (L == 6) asm volatile("s_waitcnt vmcnt(6)" ::: "memory");
  else if constexpr (L == 4) asm volatile("s_waitcnt vmcnt(4)" ::: "memory");
  else asm volatile("s_waitcnt vmcnt(0)" ::: "memory");
}

constexpr int CB = 16;       // batch
constexpr int CC = 512;      // channels
constexpr int CN = 4096;     // H*W
constexpr int CKK = 64;      // codebook size K
constexpr long MALL = (long)CB * CN;   // 65536

__device__ inline int swz8(int bid, int n) {   // bijective (n % 8 == 0)
  return (bid & 7) * (n >> 3) + (bid >> 3);
}

// ---------------------------------------------------------------------------
// K0: convert weights to fp16; init per-batch muT (K,C) and mu_ck (C,K).
__global__ __launch_bounds__(256) void prep(
    const float* __restrict__ stem_w, const float* __restrict__ head_w,
    const float* __restrict__ mu,
    half_t* __restrict__ swh, half_t* __restrict__ hwh,
    half_t* __restrict__ muT, half_t* __restrict__ muck)
{
  int i = blockIdx.x * 256 + threadIdx.x;   // grid covers C*C = 262144
  swh[i] = (half_t)stem_w[i];
  hwh[i] = (half_t)head_w[i];
  if (i < CC * CKK) {
    int c = i >> 6, k = i & 63;
    half_t v = (half_t)mu[i];               // mu is (C,K) row-major
    for (int b = 0; b < CB; ++b) {
      muT[(long)b * CKK * CC + (long)k * CC + c] = v;
      muck[(long)b * CC * CKK + i] = v;
    }
  }
}

// ---------------------------------------------------------------------------
// x (B,C,N) fp32 -> xT (B,N,C) fp16. Scalar loads: 64 lanes x 4B = 256B per
// instruction (coalescing sweet spot); scalar half stores 128B/wave.
__global__ __launch_bounds__(256) void xpose(
    const float* __restrict__ in, half_t* __restrict__ outT)
{
  __shared__ half_t t[64][65];
  const int s0 = blockIdx.x * 64, r0 = blockIdx.y * 64;   // s: N, r: C
  const long bz = blockIdx.z;
  const float* ib = in + bz * (long)CC * CN;
  half_t* ob = outT + bz * (long)CC * CN;
  const int tid = threadIdx.x, cl = tid & 63, rw = tid >> 6;
#pragma unroll
  for (int it = 0; it < 16; ++it) {
    int r = it * 4 + rw;
    t[cl][r] = (half_t)ib[(long)(r0 + r) * CN + s0 + cl];
  }
  __syncthreads();
#pragma unroll
  for (int it = 0; it < 16; ++it) {
    int s = it * 4 + rw;
    ob[(long)(s0 + s) * CC + r0 + cl] = t[s][cl];
  }
}

// ---------------------------------------------------------------------------
// Stem GEMM (single-buffer 2-phase, measured 77us): Yf (B*N, C) = xT @ Bw^T
// + bias, dual-layout epilogue also writing ycn (B,C,N). 128x128 tile,
// 33KB LDS -> 4 blocks/CU, swizzled staging, setprio.
__global__ __launch_bounds__(256) void gemm_sb(
    const half_t* __restrict__ A, const half_t* __restrict__ Bw,
    const float* __restrict__ bias,
    half_t* __restrict__ Co, half_t* __restrict__ CoT)
{
  constexpr int HB = 256 * 64;                 // halfs, single buffer
  constexpr int EPS = 128 * 132;
  constexpr int TOT = HB > EPS ? HB : EPS;
  __shared__ __align__(16) half_t smem[TOT];

  const int tid = threadIdx.x, wid = tid >> 6, lane = tid & 63;
  const int bid = swz8(blockIdx.x, gridDim.x);
  const int tm = bid >> 2, tn = bid & 3;       // 512 m-tiles x 4 n-tiles
  const half_t* Ab = A + (long)tm * 128 * CC;
  const half_t* Bb = Bw + (long)tn * 128 * CC;
  const int wr = wid >> 1, wc = wid & 1;

  const int r8 = lane >> 3;
  const int gcs = ((lane & 7) ^ r8) * 8;

  auto stage = [&](int ks) {
    half_t* dA = smem;
    half_t* dB = smem + 128 * 64;
    const half_t* ga = Ab + (long)ks * 64;
#pragma unroll
    for (int c = wid; c < 16; c += 4)
      GLD_LDS(ga + (long)(c * 8 + r8) * CC + gcs, &dA[c * 512]);
    const half_t* gb = Bb + (long)ks * 64;
#pragma unroll
    for (int c = wid; c < 16; c += 4)
      GLD_LDS(gb + (long)(c * 8 + r8) * CC + gcs, &dB[c * 512]);
  };

  f32x4 acc[4][4];
#pragma unroll
  for (int i = 0; i < 4; ++i)
#pragma unroll
    for (int j = 0; j < 4; ++j) acc[i][j] = f32x4{0.f, 0.f, 0.f, 0.f};

  for (int ks = 0; ks < 8; ++ks) {
    stage(ks);
    asm volatile("s_waitcnt vmcnt(0)" ::: "memory"); SBAR;
    RAWBAR;
    const half_t* lA = smem;
    const half_t* lB = smem + 128 * 64;
#pragma unroll
    for (int kk = 0; kk < 2; ++kk) {
      half8 af[4], bfr[4];
      const int cg = kk * 4 + (lane >> 4);
#pragma unroll
      for (int i = 0; i < 4; ++i) {
        const int rA = wr * 64 + i * 16 + (lane & 15);
        af[i] = *(const half8*)&lA[rA * 64 + ((cg ^ (rA & 7)) << 3)];
      }
#pragma unroll
      for (int j = 0; j < 4; ++j) {
        const int rB = wc * 64 + j * 16 + (lane & 15);
        bfr[j] = *(const half8*)&lB[rB * 64 + ((cg ^ (rB & 7)) << 3)];
      }
      __builtin_amdgcn_s_setprio(1);
#pragma unroll
      for (int i = 0; i < 4; ++i)
#pragma unroll
        for (int j = 0; j < 4; ++j)
          acc[i][j] = __builtin_amdgcn_mfma_f32_16x16x32_f16(af[i], bfr[j],
                                                             acc[i][j], 0, 0, 0);
      __builtin_amdgcn_s_setprio(0);
    }
    RAWBAR;
  }

  // Epilogue: ep[n-of-tile][m], pitch 132, dual-layout wide stores.
  constexpr int PIT = 132;
  half_t* ep = smem;
#pragma unroll
  for (int j = 0; j < 4; ++j) {
    const int nl = wc * 64 + j * 16 + (lane & 15);
    const float bv = bias[tn * 128 + nl];
#pragma unroll
    for (int i = 0; i < 4; ++i) {
      const int ml = wr * 64 + i * 16 + ((lane >> 4) << 2);
      half4 h;
#pragma unroll
      for (int r = 0; r < 4; ++r) h[r] = (half_t)(acc[i][j][r] + bv);
      *(half4*)&ep[nl * PIT + ml] = h;
    }
  }
  __syncthreads();
  const long row0 = (long)tm * 128;
  const long b = row0 >> 12;
  const int n0 = (int)(row0 & 4095);
  { // Yf row-major (m, o-contig)
#pragma unroll
    for (int s = 0; s < 8; ++s) {
      const int q = tid + 256 * s;
      const int m = q & 127, cc8 = q >> 7;
      half8 v;
#pragma unroll
      for (int e = 0; e < 8; ++e) v[e] = ep[(cc8 * 8 + e) * PIT + m];
      *(half8*)&Co[(row0 + m) * CC + tn * 128 + cc8 * 8] = v;
    }
  }
  { // ycn (B, o, 4096)
#pragma unroll
    for (int s = 0; s < 8; ++s) {
      const int q = tid + 256 * s;
      const int mc = q & 15, cl = q >> 4;
      half8 v = *(const half8*)&ep[cl * PIT + mc * 8];
      *(half8*)&CoT[(b * CC + tn * 128 + cl) * CN + n0 + mc * 8] = v;
    }
  }
}

// ---------------------------------------------------------------------------
// Generic fp16 GEMM, A@B^T form (v11 dbuf counted-vmcnt pipeline + swizzle).
// MODE bit0: +bias; bit1: relu; bit2: plain fp32 partial store into Cacc at
// split offset (blockIdx.y) — no atomics, regions disjoint.
// EPI bit0: LDS epilogue row-major. EPI bit1: transposed (B, Nn, 4096).
// STATS (requires EPI&2): fused per-channel sum/sumsq atomics into stats[].
template <int BM, int BN, int MODE, int EPI, bool SWZ, bool STATS>
__global__ __launch_bounds__(256) void gemm_abt(
    const half_t* __restrict__ A, const half_t* __restrict__ Bm,
    half_t* __restrict__ Co, half_t* __restrict__ CoT,
    float* __restrict__ Cacc, const float* __restrict__ bias,
    float* __restrict__ stats,
    int M, int Nn, int Kk, int ksplit, long sA, long sB, long sC)
{
  constexpr int FM = BM / 32, FN = BN / 32;
  constexpr int HB = (BM + BN) * 64;
  constexpr int LCNT = (BM / 8) / 4 + (BN / 8) / 4;
  constexpr int STG = 2 * HB;
  constexpr int EPS = (EPI != 0) ? BN * (BM + 4) : 0;
  constexpr int TOT = STG > EPS ? STG : EPS;
  __shared__ __align__(16) half_t smem[TOT];

  const int tid = threadIdx.x, wid = tid >> 6, lane = tid & 63;
  int bid = blockIdx.x;
  if constexpr (SWZ) bid = swz8(bid, gridDim.x);
  const int tilesN = Nn / BN;
  const int tm = bid / tilesN, tn = bid % tilesN;
  const long bz = blockIdx.z;
  const half_t* Ab = A + bz * sA + (long)tm * BM * Kk;
  const half_t* Bb = Bm + bz * sB + (long)tn * BN * Kk;
  const int ksteps = Kk >> 6;
  const int per = ksteps / ksplit;
  const int ks0 = blockIdx.y * per, ks1 = ks0 + per;
  const int wr = wid >> 1, wc = wid & 1;

  const int r8 = lane >> 3;
  const int gcs = ((lane & 7) ^ r8) * 8;

  auto stage = [&](int ks, int buf) {
    half_t* dA = smem + buf * HB;
    half_t* dB = dA + BM * 64;
    const half_t* ga = Ab + (long)ks * 64;
#pragma unroll
    for (int c = wid; c < BM / 8; c += 4)
      GLD_LDS(ga + (long)(c * 8 + r8) * Kk + gcs, &dA[c * 512]);
    const half_t* gb = Bb + (long)ks * 64;
#pragma unroll
    for (int c = wid; c < BN / 8; c += 4)
      GLD_LDS(gb + (long)(c * 8 + r8) * Kk + gcs, &dB[c * 512]);
  };

  f32x4 acc[FM][FN];
#pragma unroll
  for (int i = 0; i < FM; ++i)
#pragma unroll
    for (int j = 0; j < FN; ++j) acc[i][j] = f32x4{0.f, 0.f, 0.f, 0.f};

  stage(ks0, 0);
  if (ks0 + 1 < ks1) { stage(ks0 + 1, 1); vmwait<LCNT>(); }
  else               { vmwait<0>(); }
  RAWBAR;

  int cur = 0;
  for (int ks = ks0; ks < ks1; ++ks) {
    const half_t* lA = smem + cur * HB;
    const half_t* lB = lA + BM * 64;
#pragma unroll
    for (int kk = 0; kk < 2; ++kk) {
      half8 af[FM], bfr[FN];
      const int cg = kk * 4 + (lane >> 4);
#pragma unroll
      for (int i = 0; i < FM; ++i) {
        const int rA = wr * (BM / 2) + i * 16 + (lane & 15);
        af[i] = *(const half8*)&lA[rA * 64 + ((cg ^ (rA & 7)) << 3)];
      }
#pragma unroll
      for (int j = 0; j < FN; ++j) {
        const int rB = wc * (BN / 2) + j * 16 + (lane & 15);
        bfr[j] = *(const half8*)&lB[rB * 64 + ((cg ^ (rB & 7)) << 3)];
      }
      __builtin_amdgcn_s_setprio(1);
#pragma unroll
      for (int i = 0; i < FM; ++i)
#pragma unroll
        for (int j = 0; j < FN; ++j)
          acc[i][j] = __builtin_amdgcn_mfma_f32_16x16x32_f16(af[i], bfr[j],
                                                             acc[i][j], 0, 0, 0);
      __builtin_amdgcn_s_setprio(0);
    }
    RAWBAR;
    const bool more = (ks + 2 < ks1);
    if (more) { stage(ks + 2, cur); vmwait<LCNT>(); }
    else      { vmwait<0>(); }
    RAWBAR;
    cur ^= 1;
  }

  if constexpr (EPI != 0) {
    static_assert(BM == 128 && BN == 128, "LDS epilogue assumes 128x128");
    constexpr int PIT = BM + 4;
    half_t* ep = smem;
#pragma unroll
    for (int j = 0; j < FN; ++j) {
      const int nl = wc * 64 + j * 16 + (lane & 15);
      float bv = 0.f;
      if constexpr (MODE & 1) bv = bias[tn * BN + nl];
      float s1 = 0.f, s2 = 0.f;
#pragma unroll
      for (int i = 0; i < FM; ++i) {
        const int ml = wr * 64 + i * 16 + ((lane >> 4) << 2);
        half4 h;
#pragma unroll
        for (int r = 0; r < 4; ++r) {
          float v = acc[i][j][r] + bv;
          if constexpr (MODE & 2) v = fmaxf(v, 0.f);
          if constexpr (STATS) { s1 += v; s2 += v * v; }
          h[r] = (half_t)v;
        }
        *(half4*)&ep[nl * PIT + ml] = h;
      }
      if constexpr (STATS) {     // reduce 64 m-rows this wave holds (col nl)
        s1 += __shfl_xor(s1, 16); s1 += __shfl_xor(s1, 32);
        s2 += __shfl_xor(s2, 16); s2 += __shfl_xor(s2, 32);
        if (lane < 16) {
          const int ch = tn * BN + nl;
          atomicAdd(&stats[ch], s1);
          atomicAdd(&stats[CC + ch], s2);
        }
      }
    }
    __syncthreads();
    const long rowbase = (long)tm * BM;
    if constexpr (EPI & 1) {
#pragma unroll
      for (int s = 0; s < 8; ++s) {
        const int q = tid + 256 * s;
        const int m = q & 127, cc8 = q >> 7;
        half8 v;
#pragma unroll
        for (int e = 0; e < 8; ++e) v[e] = ep[(cc8 * 8 + e) * PIT + m];
        *(half8*)&Co[bz * sC + (rowbase + m) * Nn + tn * BN + cc8 * 8] = v;
      }
    }
    if constexpr (EPI & 2) {
      const long b = rowbase >> 12, nbase = rowbase & 4095;
#pragma unroll
      for (int s = 0; s < 8; ++s) {
        const int q = tid + 256 * s;
        const int mc = q & 15, cl = q >> 4;
        half8 v = *(const half8*)&ep[cl * PIT + mc * 8];
        *(half8*)&CoT[(b * Nn + tn * BN + cl) * 4096 + nbase + mc * 8] = v;
      }
    }
  } else {
#pragma unroll
    for (int j = 0; j < FN; ++j) {
      const int n = tn * BN + wc * (BN / 2) + j * 16 + (lane & 15);
      float bv = 0.f;
      if constexpr (MODE & 1) bv = bias[n];
#pragma unroll
      for (int i = 0; i < FM; ++i) {
        const int mbase = tm * BM + wr * (BM / 2) + i * 16 + ((lane >> 4) << 2);
#pragma unroll
        for (int r = 0; r < 4; ++r) {
          if constexpr ((MODE & 4) != 0) {   // per-split plain partial store
            const long idx = bz * sC + (long)blockIdx.y * ((long)BM * Nn) +
                             (long)(mbase + r) * Nn + n;
            Cacc[idx] = acc[i][j][r];
          } else {
            const long idx = bz * sC + (long)(mbase + r) * Nn + n;
            float v = acc[i][j][r] + bv;
            if constexpr ((MODE & 2) != 0) v = fmaxf(v, 0.f);
            Co[idx] = (half_t)v;
          }
        }
      }
    }
  }
}

// ---------------------------------------------------------------------------
// K3 (v11 verbatim): S = Yf @ muT^T, in-register rowwise softmax, writes zT
// always, z when zp != nullptr (final iter). Dbuf counted-vmcnt staging.
__global__ __launch_bounds__(256) void s_softmax(
    const half_t* __restrict__ Yf, const half_t* __restrict__ muT,
    half_t* __restrict__ zp, half_t* __restrict__ zT)
{
  constexpr int HB = (128 + 64) * 64;     // halfs per staging buffer
  __shared__ __align__(16) union {
    half_t st[2 * HB];                    // 48 KiB staging (dbuf)
    half_t zh[128 * 68];                  // epilogue z tile
  } sm;
  const int tid = threadIdx.x, wid = tid >> 6, lane = tid & 63;
  const int tm = blockIdx.x;
  const long bz = blockIdx.z;
  const half_t* Ab = Yf + bz * (long)CN * CC + (long)tm * 128 * CC;
  const half_t* Bb = muT + bz * (long)CKK * CC;

  const int r8 = lane >> 3;
  const int gcs = ((lane & 7) ^ r8) * 8;

  auto stage = [&](int ks, int buf) {
    half_t* dA = sm.st + buf * HB;
    half_t* dB = dA + 128 * 64;
    const half_t* ga = Ab + (long)ks * 64;
#pragma unroll
    for (int c = wid; c < 16; c += 4)
      GLD_LDS(ga + (long)(c * 8 + r8) * CC + gcs, &dA[c * 512]);
    const half_t* gb = Bb + (long)ks * 64;
#pragma unroll
    for (int c = wid; c < 8; c += 4)
      GLD_LDS(gb + (long)(c * 8 + r8) * CC + gcs, &dB[c * 512]);
  };

  f32x4 acc[2][4];
#pragma unroll
  for (int i = 0; i < 2; ++i)
#pragma unroll
    for (int j = 0; j < 4; ++j) acc[i][j] = f32x4{0.f, 0.f, 0.f, 0.f};

  stage(0, 0);
  stage(1, 1);
  vmwait<6>();
  RAWBAR;
  int cur = 0;
  for (int ks = 0; ks < 8; ++ks) {   // Kk = 512
    const half_t* lA = sm.st + cur * HB;
    const half_t* lB = lA + 128 * 64;
#pragma unroll
    for (int kk = 0; kk < 2; ++kk) {
      half8 af[2], bfr[4];
      const int cg = kk * 4 + (lane >> 4);
#pragma unroll
      for (int i = 0; i < 2; ++i) {
        const int rA = wid * 32 + i * 16 + (lane & 15);
        af[i] = *(const half8*)&lA[rA * 64 + ((cg ^ (rA & 7)) << 3)];
      }
#pragma unroll
      for (int j = 0; j < 4; ++j) {
        const int rB = j * 16 + (lane & 15);
        bfr[j] = *(const half8*)&lB[rB * 64 + ((cg ^ (rB & 7)) << 3)];
      }
      __builtin_amdgcn_s_setprio(1);
#pragma unroll
      for (int i = 0; i < 2; ++i)
#pragma unroll
        for (int j = 0; j < 4; ++j)
          acc[i][j] = __builtin_amdgcn_mfma_f32_16x16x32_f16(af[i], bfr[j],
                                                             acc[i][j], 0, 0, 0);
      __builtin_amdgcn_s_setprio(0);
    }
    RAWBAR;
    const bool more = (ks + 2 < 8);
    if (more) { stage(ks + 2, cur); vmwait<6>(); }
    else      { vmwait<0>(); }
    RAWBAR;
    cur ^= 1;
  }

  // In-register softmax over 64 cols per row.
#pragma unroll
  for (int i = 0; i < 2; ++i)
#pragma unroll
    for (int r = 0; r < 4; ++r) {
      float mx = fmaxf(fmaxf(acc[i][0][r], acc[i][1][r]),
                       fmaxf(acc[i][2][r], acc[i][3][r]));
#pragma unroll
      for (int m = 1; m < 16; m <<= 1) mx = fmaxf(mx, __shfl_xor(mx, m));
      float p[4], s = 0.f;
#pragma unroll
      for (int j = 0; j < 4; ++j) { p[j] = __expf(acc[i][j][r] - mx); s += p[j]; }
#pragma unroll
      for (int m = 1; m < 16; m <<= 1) s += __shfl_xor(s, m);
      const float inv = 1.f / s;
#pragma unroll
      for (int j = 0; j < 4; ++j) acc[i][j][r] = p[j] * inv;
    }

#pragma unroll
  for (int i = 0; i < 2; ++i)
#pragma unroll
    for (int j = 0; j < 4; ++j)
#pragma unroll
      for (int r = 0; r < 4; ++r) {
        const int row = wid * 32 + i * 16 + ((lane >> 4) << 2) + r;
        const int col = j * 16 + (lane & 15);
        sm.zh[row * 68 + col] = (half_t)acc[i][j][r];
      }
  __syncthreads();
  if (zp) { // z (N,K): rows n, contiguous k  (final iter only)
    const int nl = tid >> 1, seg = tid & 1;
    const long base = bz * (long)CN * CKK + (long)(tm * 128 + nl) * CKK + seg * 32;
#pragma unroll
    for (int g = 0; g < 4; ++g) {
      half8 v;
#pragma unroll
      for (int e = 0; e < 8; ++e) v[e] = sm.zh[nl * 68 + seg * 32 + g * 8 + e];
      *(half8*)&zp[base + g * 8] = v;
    }
  }
  { // zT (K,N): rows k, contiguous n
    const int k = tid >> 2, seg = tid & 3;
    const long base = bz * (long)CKK * CN + (long)k * CN + tm * 128 + seg * 32;
#pragma unroll
    for (int g = 0; g < 4; ++g) {
      half8 v;
#pragma unroll
      for (int e = 0; e < 8; ++e) v[e] = sm.zh[(seg * 32 + g * 8 + e) * 68 + k];
      *(half8*)&zT[base + g * 8] = v;
    }
  }
}

// ---------------------------------------------------------------------------
// mu = R / max(||R||_c, 1e-12) per (b,k), R = sum of 4 split partials.
// Writes muT (K,C) and mu_ck (C,K).
__global__ __launch_bounds__(64) void mu_norm(
    const float* __restrict__ acc, half_t* __restrict__ muT, half_t* __restrict__ muck)
{
  const int bk = blockIdx.x;           // b*64 + k
  const int b = bk >> 6, k = bk & 63;
  const float* base = acc + ((long)b * 4 * CKK + k) * CC;   // split stride K*C
  const int t = threadIdx.x;
  float v[8]; float s = 0.f;
#pragma unroll
  for (int e = 0; e < 8; ++e) {
    float a = base[t * 8 + e] + base[CKK * CC + t * 8 + e] +
              base[2 * CKK * CC + t * 8 + e] + base[3 * CKK * CC + t * 8 + e];
    v[e] = a; s += a * a;
  }
#pragma unroll
  for (int m = 1; m < 64; m <<= 1) s += __shfl_xor(s, m);
  const float inv = 1.f / fmaxf(sqrtf(s), 1e-12f);
  half8 o;
#pragma unroll
  for (int e = 0; e < 8; ++e) o[e] = (half_t)(v[e] * inv);
  *(half8*)&muT[(long)bk * CC + t * 8] = o;
  half_t* mc = muck + (long)b * CC * CKK;
#pragma unroll
  for (int e = 0; e < 8; ++e) mc[(long)(t * 8 + e) * CKK + k] = o[e];
}

// ---------------------------------------------------------------------------
__global__ void bn_param(const float* __restrict__ stats,
                         const float* __restrict__ gamma, const float* __restrict__ beta,
                         float* __restrict__ scsh)
{
  const int c = threadIdx.x;
  const float cnt = 1.f / 65536.f;
  const float mean = stats[c] * cnt;
  const float var = stats[CC + c] * cnt - mean * mean;
  const float sc = gamma[c] * rsqrtf(var + 1e-5f);
  scsh[c] = sc;
  scsh[CC + c] = beta[c] - mean * sc;
}

// ---------------------------------------------------------------------------
// out(B,C,N) = relu( hcn*sc + sh + x ), pure elementwise (hcn already (C,N)).
__global__ __launch_bounds__(256) void bn_final2(
    const half_t* __restrict__ hcn, const float* __restrict__ x,
    const float* __restrict__ scsh, float* __restrict__ out)
{
  const long i8 = (long)blockIdx.x * 256 + threadIdx.x;   // 8-elem chunk id
  const int c = (int)((i8 >> 9) & 511);
  const float sc = scsh[c], sh = scsh[CC + c];
  half8 h = *(const half8*)&hcn[i8 * 8];
  f32x4 x0 = *(const f32x4*)&x[i8 * 8];
  f32x4 x1 = *(const f32x4*)&x[i8 * 8 + 4];
  f32x4 o0, o1;
#pragma unroll
  for (int e = 0; e < 4; ++e) o0[e] = fmaxf((float)h[e] * sc + sh + x0[e], 0.f);
#pragma unroll
  for (int e = 0; e < 4; ++e) o1[e] = fmaxf((float)h[4 + e] * sc + sh + x1[e], 0.f);
  *(f32x4*)&out[i8 * 8] = o0;
  *(f32x4*)&out[i8 * 8 + 4] = o1;
}

// ---------------------------------------------------------------------------
extern "C" void kernel_launch(void* const* d_in, const int* in_sizes, int n_in,
                              void* d_out, int out_size, void* d_ws, size_t ws_size,
                              hipStream_t stream)
{
  const float* x      = (const float*)d_in[0];
  const float* mu     = (const float*)d_in[1];
  const float* stem_w = (const float*)d_in[2];
  const float* stem_b = (const float*)d_in[3];
  const float* head_w = (const float*)d_in[4];
  const float* head_b = (const float*)d_in[5];
  const float* bn_g   = (const float*)d_in[6];
  const float* bn_b   = (const float*)d_in[7];
  float* out = (float*)d_out;

  const size_t NEED = 214ull << 20;
  if (ws_size < NEED) {
    hipMemsetAsync(d_out, 0, (size_t)out_size * 4, stream);
    return;
  }
  char* ws = (char*)d_ws;
  const long MB = 1 << 20;
  half_t* xT   = (half_t*)(ws);              // 64 MiB; xT -> muacc -> y2f
  float* muacc = (float*)(ws);               //   8 MiB (b,4,K,C) fp32 partials
  half_t* y2f  = (half_t*)(ws);
  half_t* Yf   = (half_t*)(ws + 64 * MB);    // 64 MiB ; reused as hcn
  half_t* ycn  = (half_t*)(ws + 128 * MB);   // 64 MiB
  half_t* z    = (half_t*)(ws + 192 * MB);   // 8 MiB
  half_t* zT   = (half_t*)(ws + 200 * MB);   // 8 MiB
  half_t* muT  = (half_t*)(ws + 208 * MB);   // 1 MiB
  half_t* muck = (half_t*)(ws + 209 * MB);   // 1 MiB
  half_t* swh  = (half_t*)(ws + 212 * MB);
  half_t* hwh  = (half_t*)(ws + 212 * MB + 512 * 1024);
  float* stats = (float*)(ws + 213 * MB);
  float* scsh  = (float*)(ws + 213 * MB + 8 * 1024);
  half_t* hcn = Yf;    // Yf dead after final softmax

  prep<<<1024, 256, 0, stream>>>(stem_w, head_w, mu, swh, hwh, muT, muck);
  // xT (B,N,C) <- x (B,C,N)   (scalar coalesced transpose)
  xpose<<<dim3(64, 8, 16), 256, 0, stream>>>(x, xT);
  // stem: Yf (B*N,C) + ycn (B,C,N) = xT @ stem_w^T + stem_b
  gemm_sb<<<2048, 256, 0, stream>>>(xT, swh, stem_b, Yf, ycn);

  for (int it = 0; it < 3; ++it) {
    s_softmax<<<dim3(32, 1, 16), 256, 0, stream>>>(
        Yf, muT, (it == 2) ? z : nullptr, zT);
    // mu partials (K,C) per split = zT @ ycn^T (4 splits, plain stores)
    gemm_abt<64, 128, 4, 0, false, false><<<dim3(4, 4, 16), 256, 0, stream>>>(
        zT, ycn, nullptr, nullptr, muacc, nullptr, nullptr, CKK, CC, CN, 4,
        (long)CKK * CN, (long)CC * CN, (long)4 * CKK * CC);
    mu_norm<<<CB * CKK, 64, 0, stream>>>(muacc, muT, muck);
  }
  // y2f (B,N,C) = relu(z @ mu_ck^T)
  gemm_abt<128, 128, 2, 1, true, false><<<dim3(128, 1, 16), 256, 0, stream>>>(
      z, muck, y2f, nullptr, nullptr, nullptr, nullptr, CN, CC, CKK, 1,
      (long)CN * CKK, (long)CC * CKK, (long)CN * CC);
  // head: hcn (B,C,N) = (y2f @ head_w^T + head_b), BN stats fused in epilogue
  hipMemsetAsync(stats, 0, 2 * CC * sizeof(float), stream);
  gemm_abt<128, 128, 1, 2, true, true><<<dim3(2048, 1, 1), 256, 0, stream>>>(
      y2f, hwh, nullptr, hcn, nullptr, head_b, stats, (int)MALL, CC, CC, 1, 0, 0, 0);

  bn_param<<<1, 512, 0, stream>>>(stats, bn_g, bn_b, scsh);
  bn_final2<<<16384, 256, 0, stream>>>(hcn, x, scsh, out);
}

// Round 14
// 382.308 us; speedup vs baseline: 1.0434x; 1.0412x over previous
//
#include <hip/hip_runtime.h>

// EMAttention2d on MI355X — v14: v11 frozen (best measured, 383us) + two
// dispatch deletions: bn_param folded into bn_final (per-thread channel),
// stats zeroing folded into prep. B=16, C=512, N=4096, K=64, 3 EM iters.
// mu_b = colnorm_c(yf^T @ z)  (zn normalization cancels under column L2 norm).

typedef _Float16 half_t;
typedef _Float16 half4 __attribute__((ext_vector_type(4)));
typedef _Float16 half8 __attribute__((ext_vector_type(8)));
typedef float f32x4 __attribute__((ext_vector_type(4)));

#define GLD_LDS(gp, lp) __builtin_amdgcn_global_load_lds( \
    (const __attribute__((address_space(1))) void*)(gp),  \
    (__attribute__((address_space(3))) void*)(lp), 16, 0, 0)

#define SBAR __builtin_amdgcn_sched_barrier(0)
#define RAWBAR do { SBAR; __builtin_amdgcn_s_barrier(); SBAR; } while (0)
#define LGKM0 do { asm volatile("s_waitcnt lgkmcnt(0)" ::: "memory"); SBAR; } while (0)

template <int L> __device__ __forceinline__ void vmwait() {
  if constexpr (L == 8) asm volatile("s_waitcnt vmcnt(8)" ::: "memory");
  else if constexpr (L == 6) asm volatile("s_waitcnt vmcnt(6)" ::: "memory");
  else if constexpr (L == 4) asm volatile("s_waitcnt vmcnt(4)" ::: "memory");
  else asm volatile("s_waitcnt vmcnt(0)" ::: "memory");
}

constexpr int CB = 16;       // batch
constexpr int CC = 512;      // channels
constexpr int CN = 4096;     // H*W
constexpr int CKK = 64;      // codebook size K
constexpr long MALL = (long)CB * CN;   // 65536

__device__ inline int swz8(int bid, int n) {   // bijective (n % 8 == 0)
  return (bid & 7) * (n >> 3) + (bid >> 3);
}

// ---------------------------------------------------------------------------
// K0: convert weights to fp16; init per-batch muT (K,C) and mu_ck (C,K);
// zero the BN stats accumulator (block 1023 tail threads).
__global__ __launch_bounds__(256) void prep(
    const float* __restrict__ stem_w, const float* __restrict__ head_w,
    const float* __restrict__ mu,
    half_t* __restrict__ swh, half_t* __restrict__ hwh,
    half_t* __restrict__ muT, half_t* __restrict__ muck,
    float* __restrict__ stats)
{
  int i = blockIdx.x * 256 + threadIdx.x;   // grid covers C*C = 262144
  swh[i] = (half_t)stem_w[i];
  hwh[i] = (half_t)head_w[i];
  if (i < CC * CKK) {
    int c = i >> 6, k = i & 63;
    half_t v = (half_t)mu[i];               // mu is (C,K) row-major
    for (int b = 0; b < CB; ++b) {
      muT[(long)b * CKK * CC + (long)k * CC + c] = v;
      muck[(long)b * CC * CKK + i] = v;
    }
  }
  if (blockIdx.x < 4) {                     // zero stats[1024]
    stats[blockIdx.x * 256 + threadIdx.x] = 0.f;
  }
}

// ---------------------------------------------------------------------------
// Stem GEMM fused with x-transpose (v11 verbatim): Yf[m][o] = sum_c
// x[b][c][n]*W[o][c]+bias, m = b*4096+n. A-tile (64c x 128n) reg-staged from
// fp32 x, transposed+converted into swizzled LDS; dbuf.
template <bool SWZ>
__global__ __launch_bounds__(256) void gemm_stem(
    const float* __restrict__ X, const half_t* __restrict__ Bw,
    const float* __restrict__ bias,
    half_t* __restrict__ Co, half_t* __restrict__ CoT)
{
  constexpr int SAB = 16384;                    // halfs per dbuf set (A+B)
  __shared__ __align__(16) half_t smem[2 * SAB];   // 64 KiB (epi reuses)
  const int tid = threadIdx.x, wid = tid >> 6, lane = tid & 63;
  int bid = blockIdx.x;
  if constexpr (SWZ) bid = swz8(bid, gridDim.x);
  const int tm = bid >> 2, tn = bid & 3;        // 512 m-tiles x 4 n-tiles
  const long row0 = (long)tm * 128;
  const long b = row0 >> 12;
  const int n0 = (int)(row0 & 4095);
  const float* Xb = X + b * ((long)CC * CN) + n0;
  const half_t* Bb = Bw + (long)tn * 128 * CC;
  const int wr = wid >> 1, wc = wid & 1;

  const int an = tid & 127;                     // A: thread n
  const int ac0 = (tid >> 7) * 32;              // A: c-half 0/32
  const int r8 = lane >> 3;
  const int gcs = ((lane & 7) ^ r8) * 8;        // B pre-swizzled source col

  float va[32];
  auto issueA = [&](int ks) {
    const float* p = Xb + (long)(ks * 64 + ac0) * CN + an;
#pragma unroll
    for (int e = 0; e < 32; ++e) va[e] = p[(long)e * CN];
  };
  auto writeA = [&](int buf) {
    half_t* dA = smem + buf * SAB;
#pragma unroll
    for (int g = 0; g < 4; ++g) {
      half8 h;
#pragma unroll
      for (int e = 0; e < 8; ++e) h[e] = (half_t)va[g * 8 + e];
      const int chunk = (ac0 >> 3) + g;         // 0..7
      *(half8*)&dA[an * 64 + ((chunk ^ (an & 7)) << 3)] = h;
    }
  };
  auto stageB = [&](int ks, int buf) {
    half_t* dB = smem + buf * SAB + 8192;
    const half_t* gb = Bb + (long)ks * 64;
#pragma unroll
    for (int c = wid; c < 16; c += 4)
      GLD_LDS(gb + (long)(c * 8 + r8) * CC + gcs, &dB[c * 512]);
  };

  f32x4 acc[4][4];
#pragma unroll
  for (int i = 0; i < 4; ++i)
#pragma unroll
    for (int j = 0; j < 4; ++j) acc[i][j] = f32x4{0.f, 0.f, 0.f, 0.f};

  issueA(0);
  stageB(0, 0);
  vmwait<0>();
  writeA(0);
  LGKM0;
  RAWBAR;

  int cur = 0;
  for (int ks = 0; ks < 8; ++ks) {
    if (ks < 7) { issueA(ks + 1); stageB(ks + 1, cur ^ 1); }
    const half_t* lA = smem + cur * SAB;
    const half_t* lB = lA + 8192;
#pragma unroll
    for (int kk = 0; kk < 2; ++kk) {
      half8 af[4], bfr[4];
      const int cg = kk * 4 + (lane >> 4);
#pragma unroll
      for (int i = 0; i < 4; ++i) {
        const int rA = wr * 64 + i * 16 + (lane & 15);
        af[i] = *(const half8*)&lA[rA * 64 + ((cg ^ (rA & 7)) << 3)];
      }
#pragma unroll
      for (int j = 0; j < 4; ++j) {
        const int rB = wc * 64 + j * 16 + (lane & 15);
        bfr[j] = *(const half8*)&lB[rB * 64 + ((cg ^ (rB & 7)) << 3)];
      }
      __builtin_amdgcn_s_setprio(1);
#pragma unroll
      for (int i = 0; i < 4; ++i)
#pragma unroll
        for (int j = 0; j < 4; ++j)
          acc[i][j] = __builtin_amdgcn_mfma_f32_16x16x32_f16(af[i], bfr[j],
                                                             acc[i][j], 0, 0, 0);
      __builtin_amdgcn_s_setprio(0);
    }
    RAWBAR;                       // all waves done reading buf[cur]
    if (ks < 7) {
      vmwait<0>();                // A regs + B lds arrived
      writeA(cur ^ 1);
      LGKM0;
    }
    RAWBAR;                       // buf[cur^1] fully ready
    cur ^= 1;
  }

  // Epilogue: ep[n-of-tile (o)][m], pitch 132, dual-layout wide stores.
  constexpr int PIT = 132;
  half_t* ep = smem;
#pragma unroll
  for (int j = 0; j < 4; ++j) {
    const int nl = wc * 64 + j * 16 + (lane & 15);
    const float bv = bias[tn * 128 + nl];
#pragma unroll
    for (int i = 0; i < 4; ++i) {
      const int ml = wr * 64 + i * 16 + ((lane >> 4) << 2);
      half4 h;
#pragma unroll
      for (int r = 0; r < 4; ++r) h[r] = (half_t)(acc[i][j][r] + bv);
      *(half4*)&ep[nl * PIT + ml] = h;
    }
  }
  __syncthreads();
  { // Yf row-major (m, o-contig)
#pragma unroll
    for (int s = 0; s < 8; ++s) {
      const int q = tid + 256 * s;
      const int m = q & 127, cc8 = q >> 7;
      half8 v;
#pragma unroll
      for (int e = 0; e < 8; ++e) v[e] = ep[(cc8 * 8 + e) * PIT + m];
      *(half8*)&Co[(row0 + m) * CC + tn * 128 + cc8 * 8] = v;
    }
  }
  { // ycn (B, o, 4096)
#pragma unroll
    for (int s = 0; s < 8; ++s) {
      const int q = tid + 256 * s;
      const int mc = q & 15, cl = q >> 4;
      half8 v = *(const half8*)&ep[cl * PIT + mc * 8];
      *(half8*)&CoT[(b * CC + tn * 128 + cl) * CN + n0 + mc * 8] = v;
    }
  }
}

// ---------------------------------------------------------------------------
// Generic fp16 GEMM, A@B^T form (v11 dbuf counted-vmcnt pipeline + swizzle).
// MODE bit0: +bias; bit1: relu; bit2: plain fp32 partial store into Cacc at
// split offset (blockIdx.y) — no atomics, regions disjoint.
// EPI bit0: LDS epilogue row-major. EPI bit1: transposed (B, Nn, 4096).
// STATS (requires EPI&2): fused per-channel sum/sumsq atomics into stats[].
template <int BM, int BN, int MODE, int EPI, bool SWZ, bool STATS>
__global__ __launch_bounds__(256) void gemm_abt(
    const half_t* __restrict__ A, const half_t* __restrict__ Bm,
    half_t* __restrict__ Co, half_t* __restrict__ CoT,
    float* __restrict__ Cacc, const float* __restrict__ bias,
    float* __restrict__ stats,
    int M, int Nn, int Kk, int ksplit, long sA, long sB, long sC)
{
  constexpr int FM = BM / 32, FN = BN / 32;
  constexpr int HB = (BM + BN) * 64;
  constexpr int LCNT = (BM / 8) / 4 + (BN / 8) / 4;
  constexpr int STG = 2 * HB;
  constexpr int EPS = (EPI != 0) ? BN * (BM + 4) : 0;
  constexpr int TOT = STG > EPS ? STG : EPS;
  __shared__ __align__(16) half_t smem[TOT];

  const int tid = threadIdx.x, wid = tid >> 6, lane = tid & 63;
  int bid = blockIdx.x;
  if constexpr (SWZ) bid = swz8(bid, gridDim.x);
  const int tilesN = Nn / BN;
  const int tm = bid / tilesN, tn = bid % tilesN;
  const long bz = blockIdx.z;
  const half_t* Ab = A + bz * sA + (long)tm * BM * Kk;
  const half_t* Bb = Bm + bz * sB + (long)tn * BN * Kk;
  const int ksteps = Kk >> 6;
  const int per = ksteps / ksplit;
  const int ks0 = blockIdx.y * per, ks1 = ks0 + per;
  const int wr = wid >> 1, wc = wid & 1;

  const int r8 = lane >> 3;
  const int gcs = ((lane & 7) ^ r8) * 8;

  auto stage = [&](int ks, int buf) {
    half_t* dA = smem + buf * HB;
    half_t* dB = dA + BM * 64;
    const half_t* ga = Ab + (long)ks * 64;
#pragma unroll
    for (int c = wid; c < BM / 8; c += 4)
      GLD_LDS(ga + (long)(c * 8 + r8) * Kk + gcs, &dA[c * 512]);
    const half_t* gb = Bb + (long)ks * 64;
#pragma unroll
    for (int c = wid; c < BN / 8; c += 4)
      GLD_LDS(gb + (long)(c * 8 + r8) * Kk + gcs, &dB[c * 512]);
  };

  f32x4 acc[FM][FN];
#pragma unroll
  for (int i = 0; i < FM; ++i)
#pragma unroll
    for (int j = 0; j < FN; ++j) acc[i][j] = f32x4{0.f, 0.f, 0.f, 0.f};

  stage(ks0, 0);
  if (ks0 + 1 < ks1) { stage(ks0 + 1, 1); vmwait<LCNT>(); }
  else               { vmwait<0>(); }
  RAWBAR;

  int cur = 0;
  for (int ks = ks0; ks < ks1; ++ks) {
    const half_t* lA = smem + cur * HB;
    const half_t* lB = lA + BM * 64;
#pragma unroll
    for (int kk = 0; kk < 2; ++kk) {
      half8 af[FM], bfr[FN];
      const int cg = kk * 4 + (lane >> 4);
#pragma unroll
      for (int i = 0; i < FM; ++i) {
        const int rA = wr * (BM / 2) + i * 16 + (lane & 15);
        af[i] = *(const half8*)&lA[rA * 64 + ((cg ^ (rA & 7)) << 3)];
      }
#pragma unroll
      for (int j = 0; j < FN; ++j) {
        const int rB = wc * (BN / 2) + j * 16 + (lane & 15);
        bfr[j] = *(const half8*)&lB[rB * 64 + ((cg ^ (rB & 7)) << 3)];
      }
      __builtin_amdgcn_s_setprio(1);
#pragma unroll
      for (int i = 0; i < FM; ++i)
#pragma unroll
        for (int j = 0; j < FN; ++j)
          acc[i][j] = __builtin_amdgcn_mfma_f32_16x16x32_f16(af[i], bfr[j],
                                                             acc[i][j], 0, 0, 0);
      __builtin_amdgcn_s_setprio(0);
    }
    RAWBAR;
    const bool more = (ks + 2 < ks1);
    if (more) { stage(ks + 2, cur); vmwait<LCNT>(); }
    else      { vmwait<0>(); }
    RAWBAR;
    cur ^= 1;
  }

  if constexpr (EPI != 0) {
    static_assert(BM == 128 && BN == 128, "LDS epilogue assumes 128x128");
    constexpr int PIT = BM + 4;
    half_t* ep = smem;
#pragma unroll
    for (int j = 0; j < FN; ++j) {
      const int nl = wc * 64 + j * 16 + (lane & 15);
      float bv = 0.f;
      if constexpr (MODE & 1) bv = bias[tn * BN + nl];
      float s1 = 0.f, s2 = 0.f;
#pragma unroll
      for (int i = 0; i < FM; ++i) {
        const int ml = wr * 64 + i * 16 + ((lane >> 4) << 2);
        half4 h;
#pragma unroll
        for (int r = 0; r < 4; ++r) {
          float v = acc[i][j][r] + bv;
          if constexpr (MODE & 2) v = fmaxf(v, 0.f);
          if constexpr (STATS) { s1 += v; s2 += v * v; }
          h[r] = (half_t)v;
        }
        *(half4*)&ep[nl * PIT + ml] = h;
      }
      if constexpr (STATS) {     // reduce 64 m-rows this wave holds (col nl)
        s1 += __shfl_xor(s1, 16); s1 += __shfl_xor(s1, 32);
        s2 += __shfl_xor(s2, 16); s2 += __shfl_xor(s2, 32);
        if (lane < 16) {
          const int ch = tn * BN + nl;
          atomicAdd(&stats[ch], s1);
          atomicAdd(&stats[CC + ch], s2);
        }
      }
    }
    __syncthreads();
    const long rowbase = (long)tm * BM;
    if constexpr (EPI & 1) {
#pragma unroll
      for (int s = 0; s < 8; ++s) {
        const int q = tid + 256 * s;
        const int m = q & 127, cc8 = q >> 7;
        half8 v;
#pragma unroll
        for (int e = 0; e < 8; ++e) v[e] = ep[(cc8 * 8 + e) * PIT + m];
        *(half8*)&Co[bz * sC + (rowbase + m) * Nn + tn * BN + cc8 * 8] = v;
      }
    }
    if constexpr (EPI & 2) {
      const long b = rowbase >> 12, nbase = rowbase & 4095;
#pragma unroll
      for (int s = 0; s < 8; ++s) {
        const int q = tid + 256 * s;
        const int mc = q & 15, cl = q >> 4;
        half8 v = *(const half8*)&ep[cl * PIT + mc * 8];
        *(half8*)&CoT[(b * Nn + tn * BN + cl) * 4096 + nbase + mc * 8] = v;
      }
    }
  } else {
#pragma unroll
    for (int j = 0; j < FN; ++j) {
      const int n = tn * BN + wc * (BN / 2) + j * 16 + (lane & 15);
      float bv = 0.f;
      if constexpr (MODE & 1) bv = bias[n];
#pragma unroll
      for (int i = 0; i < FM; ++i) {
        const int mbase = tm * BM + wr * (BM / 2) + i * 16 + ((lane >> 4) << 2);
#pragma unroll
        for (int r = 0; r < 4; ++r) {
          if constexpr ((MODE & 4) != 0) {   // per-split plain partial store
            const long idx = bz * sC + (long)blockIdx.y * ((long)BM * Nn) +
                             (long)(mbase + r) * Nn + n;
            Cacc[idx] = acc[i][j][r];
          } else {
            const long idx = bz * sC + (long)(mbase + r) * Nn + n;
            float v = acc[i][j][r] + bv;
            if constexpr ((MODE & 2) != 0) v = fmaxf(v, 0.f);
            Co[idx] = (half_t)v;
          }
        }
      }
    }
  }
}

// ---------------------------------------------------------------------------
// K3 (v11 verbatim): S = Yf @ muT^T, in-register rowwise softmax, writes zT
// always, z when zp != nullptr (final iter). Dbuf counted-vmcnt staging.
__global__ __launch_bounds__(256) void s_softmax(
    const half_t* __restrict__ Yf, const half_t* __restrict__ muT,
    half_t* __restrict__ zp, half_t* __restrict__ zT)
{
  constexpr int HB = (128 + 64) * 64;     // halfs per staging buffer
  __shared__ __align__(16) union {
    half_t st[2 * HB];                    // 48 KiB staging (dbuf)
    half_t zh[128 * 68];                  // epilogue z tile
  } sm;
  const int tid = threadIdx.x, wid = tid >> 6, lane = tid & 63;
  const int tm = blockIdx.x;
  const long bz = blockIdx.z;
  const half_t* Ab = Yf + bz * (long)CN * CC + (long)tm * 128 * CC;
  const half_t* Bb = muT + bz * (long)CKK * CC;

  const int r8 = lane >> 3;
  const int gcs = ((lane & 7) ^ r8) * 8;

  auto stage = [&](int ks, int buf) {
    half_t* dA = sm.st + buf * HB;
    half_t* dB = dA + 128 * 64;
    const half_t* ga = Ab + (long)ks * 64;
#pragma unroll
    for (int c = wid; c < 16; c += 4)
      GLD_LDS(ga + (long)(c * 8 + r8) * CC + gcs, &dA[c * 512]);
    const half_t* gb = Bb + (long)ks * 64;
#pragma unroll
    for (int c = wid; c < 8; c += 4)
      GLD_LDS(gb + (long)(c * 8 + r8) * CC + gcs, &dB[c * 512]);
  };

  f32x4 acc[2][4];
#pragma unroll
  for (int i = 0; i < 2; ++i)
#pragma unroll
    for (int j = 0; j < 4; ++j) acc[i][j] = f32x4{0.f, 0.f, 0.f, 0.f};

  stage(0, 0);
  stage(1, 1);
  vmwait<6>();
  RAWBAR;
  int cur = 0;
  for (int ks = 0; ks < 8; ++ks) {   // Kk = 512
    const half_t* lA = sm.st + cur * HB;
    const half_t* lB = lA + 128 * 64;
#pragma unroll
    for (int kk = 0; kk < 2; ++kk) {
      half8 af[2], bfr[4];
      const int cg = kk * 4 + (lane >> 4);
#pragma unroll
      for (int i = 0; i < 2; ++i) {
        const int rA = wid * 32 + i * 16 + (lane & 15);
        af[i] = *(const half8*)&lA[rA * 64 + ((cg ^ (rA & 7)) << 3)];
      }
#pragma unroll
      for (int j = 0; j < 4; ++j) {
        const int rB = j * 16 + (lane & 15);
        bfr[j] = *(const half8*)&lB[rB * 64 + ((cg ^ (rB & 7)) << 3)];
      }
      __builtin_amdgcn_s_setprio(1);
#pragma unroll
      for (int i = 0; i < 2; ++i)
#pragma unroll
        for (int j = 0; j < 4; ++j)
          acc[i][j] = __builtin_amdgcn_mfma_f32_16x16x32_f16(af[i], bfr[j],
                                                             acc[i][j], 0, 0, 0);
      __builtin_amdgcn_s_setprio(0);
    }
    RAWBAR;
    const bool more = (ks + 2 < 8);
    if (more) { stage(ks + 2, cur); vmwait<6>(); }
    else      { vmwait<0>(); }
    RAWBAR;
    cur ^= 1;
  }

  // In-register softmax over 64 cols per row.
#pragma unroll
  for (int i = 0; i < 2; ++i)
#pragma unroll
    for (int r = 0; r < 4; ++r) {
      float mx = fmaxf(fmaxf(acc[i][0][r], acc[i][1][r]),
                       fmaxf(acc[i][2][r], acc[i][3][r]));
#pragma unroll
      for (int m = 1; m < 16; m <<= 1) mx = fmaxf(mx, __shfl_xor(mx, m));
      float p[4], s = 0.f;
#pragma unroll
      for (int j = 0; j < 4; ++j) { p[j] = __expf(acc[i][j][r] - mx); s += p[j]; }
#pragma unroll
      for (int m = 1; m < 16; m <<= 1) s += __shfl_xor(s, m);
      const float inv = 1.f / s;
#pragma unroll
      for (int j = 0; j < 4; ++j) acc[i][j][r] = p[j] * inv;
    }

#pragma unroll
  for (int i = 0; i < 2; ++i)
#pragma unroll
    for (int j = 0; j < 4; ++j)
#pragma unroll
      for (int r = 0; r < 4; ++r) {
        const int row = wid * 32 + i * 16 + ((lane >> 4) << 2) + r;
        const int col = j * 16 + (lane & 15);
        sm.zh[row * 68 + col] = (half_t)acc[i][j][r];
      }
  __syncthreads();
  if (zp) { // z (N,K): rows n, contiguous k  (final iter only)
    const int nl = tid >> 1, seg = tid & 1;
    const long base = bz * (long)CN * CKK + (long)(tm * 128 + nl) * CKK + seg * 32;
#pragma unroll
    for (int g = 0; g < 4; ++g) {
      half8 v;
#pragma unroll
      for (int e = 0; e < 8; ++e) v[e] = sm.zh[nl * 68 + seg * 32 + g * 8 + e];
      *(half8*)&zp[base + g * 8] = v;
    }
  }
  { // zT (K,N): rows k, contiguous n
    const int k = tid >> 2, seg = tid & 3;
    const long base = bz * (long)CKK * CN + (long)k * CN + tm * 128 + seg * 32;
#pragma unroll
    for (int g = 0; g < 4; ++g) {
      half8 v;
#pragma unroll
      for (int e = 0; e < 8; ++e) v[e] = sm.zh[(seg * 32 + g * 8 + e) * 68 + k];
      *(half8*)&zT[base + g * 8] = v;
    }
  }
}

// ---------------------------------------------------------------------------
// mu = R / max(||R||_c, 1e-12) per (b,k), R = sum of 4 split partials.
// Writes muT (K,C) and mu_ck (C,K).
__global__ __launch_bounds__(64) void mu_norm(
    const float* __restrict__ acc, half_t* __restrict__ muT, half_t* __restrict__ muck)
{
  const int bk = blockIdx.x;           // b*64 + k
  const int b = bk >> 6, k = bk & 63;
  const float* base = acc + ((long)b * 4 * CKK + k) * CC;   // split stride K*C
  const int t = threadIdx.x;
  float v[8]; float s = 0.f;
#pragma unroll
  for (int e = 0; e < 8; ++e) {
    float a = base[t * 8 + e] + base[CKK * CC + t * 8 + e] +
              base[2 * CKK * CC + t * 8 + e] + base[3 * CKK * CC + t * 8 + e];
    v[e] = a; s += a * a;
  }
#pragma unroll
  for (int m = 1; m < 64; m <<= 1) s += __shfl_xor(s, m);
  const float inv = 1.f / fmaxf(sqrtf(s), 1e-12f);
  half8 o;
#pragma unroll
  for (int e = 0; e < 8; ++e) o[e] = (half_t)(v[e] * inv);
  *(half8*)&muT[(long)bk * CC + t * 8] = o;
  half_t* mc = muck + (long)b * CC * CKK;
#pragma unroll
  for (int e = 0; e < 8; ++e) mc[(long)(t * 8 + e) * CKK + k] = o[e];
}

// ---------------------------------------------------------------------------
// out(B,C,N) = relu( BN(hcn) + x ); BN params computed inline per thread from
// stats (each thread owns exactly one channel c).
__global__ __launch_bounds__(256) void bn_final3(
    const half_t* __restrict__ hcn, const float* __restrict__ x,
    const float* __restrict__ stats,
    const float* __restrict__ gamma, const float* __restrict__ beta,
    float* __restrict__ out)
{
  const long i8 = (long)blockIdx.x * 256 + threadIdx.x;   // 8-elem chunk id
  const int c = (int)((i8 >> 9) & 511);
  const float cnt = 1.f / 65536.f;
  const float mean = stats[c] * cnt;
  const float var = stats[CC + c] * cnt - mean * mean;
  const float sc = gamma[c] * rsqrtf(var + 1e-5f);
  const float sh = beta[c] - mean * sc;
  half8 h = *(const half8*)&hcn[i8 * 8];
  f32x4 x0 = *(const f32x4*)&x[i8 * 8];
  f32x4 x1 = *(const f32x4*)&x[i8 * 8 + 4];
  f32x4 o0, o1;
#pragma unroll
  for (int e = 0; e < 4; ++e) o0[e] = fmaxf((float)h[e] * sc + sh + x0[e], 0.f);
#pragma unroll
  for (int e = 0; e < 4; ++e) o1[e] = fmaxf((float)h[4 + e] * sc + sh + x1[e], 0.f);
  *(f32x4*)&out[i8 * 8] = o0;
  *(f32x4*)&out[i8 * 8 + 4] = o1;
}

// ---------------------------------------------------------------------------
extern "C" void kernel_launch(void* const* d_in, const int* in_sizes, int n_in,
                              void* d_out, int out_size, void* d_ws, size_t ws_size,
                              hipStream_t stream)
{
  const float* x      = (const float*)d_in[0];
  const float* mu     = (const float*)d_in[1];
  const float* stem_w = (const float*)d_in[2];
  const float* stem_b = (const float*)d_in[3];
  const float* head_w = (const float*)d_in[4];
  const float* head_b = (const float*)d_in[5];
  const float* bn_g   = (const float*)d_in[6];
  const float* bn_b   = (const float*)d_in[7];
  float* out = (float*)d_out;

  const size_t NEED = 214ull << 20;
  if (ws_size < NEED) {
    hipMemsetAsync(d_out, 0, (size_t)out_size * 4, stream);
    return;
  }
  char* ws = (char*)d_ws;
  const long MB = 1 << 20;
  half_t* y2f  = (half_t*)(ws);              // 64 MiB; during EM loop reused:
  float* muacc = (float*)(ws);               //   8 MiB (b,4,K,C) fp32 partials
  half_t* Yf   = (half_t*)(ws + 64 * MB);    // 64 MiB ; reused as hcn
  half_t* ycn  = (half_t*)(ws + 128 * MB);   // 64 MiB
  half_t* z    = (half_t*)(ws + 192 * MB);   // 8 MiB
  half_t* zT   = (half_t*)(ws + 200 * MB);   // 8 MiB
  half_t* muT  = (half_t*)(ws + 208 * MB);   // 1 MiB
  half_t* muck = (half_t*)(ws + 209 * MB);   // 1 MiB
  half_t* swh  = (half_t*)(ws + 212 * MB);
  half_t* hwh  = (half_t*)(ws + 212 * MB + 512 * 1024);
  float* stats = (float*)(ws + 213 * MB);
  half_t* hcn = Yf;    // Yf dead after final softmax

  prep<<<1024, 256, 0, stream>>>(stem_w, head_w, mu, swh, hwh, muT, muck, stats);
  // stem (fused x-transpose): Yf (B*N,C) + ycn (B,C,N) from fp32 x directly
  gemm_stem<true><<<2048, 256, 0, stream>>>(x, swh, stem_b, Yf, ycn);

  for (int it = 0; it < 3; ++it) {
    s_softmax<<<dim3(32, 1, 16), 256, 0, stream>>>(
        Yf, muT, (it == 2) ? z : nullptr, zT);
    // mu partials (K,C) per split = zT @ ycn^T (4 splits, plain stores)
    gemm_abt<64, 128, 4, 0, false, false><<<dim3(4, 4, 16), 256, 0, stream>>>(
        zT, ycn, nullptr, nullptr, muacc, nullptr, nullptr, CKK, CC, CN, 4,
        (long)CKK * CN, (long)CC * CN, (long)4 * CKK * CC);
    mu_norm<<<CB * CKK, 64, 0, stream>>>(muacc, muT, muck);
  }
  // y2f (B,N,C) = relu(z @ mu_ck^T)   (y2f slot free again after EM loop)
  gemm_abt<128, 128, 2, 1, true, false><<<dim3(128, 1, 16), 256, 0, stream>>>(
      z, muck, y2f, nullptr, nullptr, nullptr, nullptr, CN, CC, CKK, 1,
      (long)CN * CKK, (long)CC * CKK, (long)CN * CC);
  // head: hcn (B,C,N) = (y2f @ head_w^T + head_b), BN stats fused in epilogue
  gemm_abt<128, 128, 1, 2, true, true><<<dim3(2048, 1, 1), 256, 0, stream>>>(
      y2f, hwh, nullptr, hcn, nullptr, head_b, stats, (int)MALL, CC, CC, 1, 0, 0, 0);

  // out = relu(BN(hcn) + x), BN params inline from stats
  bn_final3<<<16384, 256, 0, stream>>>(hcn, x, stats, bn_g, bn_b, out);
}

// Round 15
// 380.422 us; speedup vs baseline: 1.0486x; 1.0050x over previous
//
#include <hip/hip_runtime.h>

// EMAttention2d on MI355X — v15: v14 + stem LDS 64->48 KB (B weights single-
// buffered, L2-resident; A stays reg-staged dbuf) => 3 blocks/CU on the stem.
// B=16, C=512, N=4096, K=64, 3 EM iters.
// mu_b = colnorm_c(yf^T @ z)  (zn normalization cancels under column L2 norm).

typedef _Float16 half_t;
typedef _Float16 half4 __attribute__((ext_vector_type(4)));
typedef _Float16 half8 __attribute__((ext_vector_type(8)));
typedef float f32x4 __attribute__((ext_vector_type(4)));

#define GLD_LDS(gp, lp) __builtin_amdgcn_global_load_lds( \
    (const __attribute__((address_space(1))) void*)(gp),  \
    (__attribute__((address_space(3))) void*)(lp), 16, 0, 0)

#define SBAR __builtin_amdgcn_sched_barrier(0)
#define RAWBAR do { SBAR; __builtin_amdgcn_s_barrier(); SBAR; } while (0)
#define LGKM0 do { asm volatile("s_waitcnt lgkmcnt(0)" ::: "memory"); SBAR; } while (0)

template <int L> __device__ __forceinline__ void vmwait() {
  if constexpr (L == 32) asm volatile("s_waitcnt vmcnt(32)" ::: "memory");
  else if constexpr (L == 8) asm volatile("s_waitcnt vmcnt(8)" ::: "memory");
  else if constexpr (L == 6) asm volatile("s_waitcnt vmcnt(6)" ::: "memory");
  else if constexpr (L == 4) asm volatile("s_waitcnt vmcnt(4)" ::: "memory");
  else asm volatile("s_waitcnt vmcnt(0)" ::: "memory");
}

constexpr int CB = 16;       // batch
constexpr int CC = 512;      // channels
constexpr int CN = 4096;     // H*W
constexpr int CKK = 64;      // codebook size K
constexpr long MALL = (long)CB * CN;   // 65536

__device__ inline int swz8(int bid, int n) {   // bijective (n % 8 == 0)
  return (bid & 7) * (n >> 3) + (bid >> 3);
}

// ---------------------------------------------------------------------------
// K0: convert weights to fp16; init per-batch muT (K,C) and mu_ck (C,K);
// zero the BN stats accumulator.
__global__ __launch_bounds__(256) void prep(
    const float* __restrict__ stem_w, const float* __restrict__ head_w,
    const float* __restrict__ mu,
    half_t* __restrict__ swh, half_t* __restrict__ hwh,
    half_t* __restrict__ muT, half_t* __restrict__ muck,
    float* __restrict__ stats)
{
  int i = blockIdx.x * 256 + threadIdx.x;   // grid covers C*C = 262144
  swh[i] = (half_t)stem_w[i];
  hwh[i] = (half_t)head_w[i];
  if (i < CC * CKK) {
    int c = i >> 6, k = i & 63;
    half_t v = (half_t)mu[i];               // mu is (C,K) row-major
    for (int b = 0; b < CB; ++b) {
      muT[(long)b * CKK * CC + (long)k * CC + c] = v;
      muck[(long)b * CC * CKK + i] = v;
    }
  }
  if (blockIdx.x < 4) {                     // zero stats[1024]
    stats[blockIdx.x * 256 + threadIdx.x] = 0.f;
  }
}

// ---------------------------------------------------------------------------
// Stem GEMM fused with x-transpose: Yf[m][o] = sum_c x[b][c][n]*W[o][c]+bias,
// m = b*4096+n. A-tile (64c x 128n) reg-staged from fp32 x (issued one step
// early), transposed+converted into swizzled LDS (double-buffered, 2x16 KB).
// B (weights, L2-resident) single-buffered 16 KB -> 48 KB LDS, 3 blocks/CU.
template <bool SWZ>
__global__ __launch_bounds__(256) void gemm_stem(
    const float* __restrict__ X, const half_t* __restrict__ Bw,
    const float* __restrict__ bias,
    half_t* __restrict__ Co, half_t* __restrict__ CoT)
{
  // layout: A0 [0,8192) | A1 [8192,16384) | B [16384,24576)  (halfs)
  __shared__ __align__(16) half_t smem[24576];   // 48 KiB (epi reuses 33 KiB)
  const int tid = threadIdx.x, wid = tid >> 6, lane = tid & 63;
  int bid = blockIdx.x;
  if constexpr (SWZ) bid = swz8(bid, gridDim.x);
  const int tm = bid >> 2, tn = bid & 3;        // 512 m-tiles x 4 n-tiles
  const long row0 = (long)tm * 128;
  const long b = row0 >> 12;
  const int n0 = (int)(row0 & 4095);
  const float* Xb = X + b * ((long)CC * CN) + n0;
  const half_t* Bb = Bw + (long)tn * 128 * CC;
  const int wr = wid >> 1, wc = wid & 1;

  const int an = tid & 127;                     // A: thread n
  const int ac0 = (tid >> 7) * 32;              // A: c-half 0/32
  const int r8 = lane >> 3;
  const int gcs = ((lane & 7) ^ r8) * 8;        // B pre-swizzled source col

  float va[32];
  auto issueA = [&](int ks) {
    const float* p = Xb + (long)(ks * 64 + ac0) * CN + an;
#pragma unroll
    for (int e = 0; e < 32; ++e) va[e] = p[(long)e * CN];
  };
  auto writeA = [&](int buf) {
    half_t* dA = smem + buf * 8192;
#pragma unroll
    for (int g = 0; g < 4; ++g) {
      half8 h;
#pragma unroll
      for (int e = 0; e < 8; ++e) h[e] = (half_t)va[g * 8 + e];
      const int chunk = (ac0 >> 3) + g;         // 0..7
      *(half8*)&dA[an * 64 + ((chunk ^ (an & 7)) << 3)] = h;
    }
  };
  auto stageB = [&](int ks) {                   // single buffer
    half_t* dB = smem + 16384;
    const half_t* gb = Bb + (long)ks * 64;
#pragma unroll
    for (int c = wid; c < 16; c += 4)
      GLD_LDS(gb + (long)(c * 8 + r8) * CC + gcs, &dB[c * 512]);
  };

  f32x4 acc[4][4];
#pragma unroll
  for (int i = 0; i < 4; ++i)
#pragma unroll
    for (int j = 0; j < 4; ++j) acc[i][j] = f32x4{0.f, 0.f, 0.f, 0.f};

  // prologue: A(0) + B(0)
  issueA(0);
  stageB(0);
  vmwait<0>();
  writeA(0);
  LGKM0;
  RAWBAR;

  int cur = 0;
  for (int ks = 0; ks < 8; ++ks) {
    // B(ks) already staged for ks==0; restage for ks>0 (B buf free since the
    // post-compute barrier of step ks-1).
    if (ks > 0) stageB(ks);
    if (ks < 7) issueA(ks + 1);     // HBM reg loads fly across compute
    if (ks > 0) {
      if (ks < 7) vmwait<32>();     // drain only B's 4 oldest; A stays in flight
      else        vmwait<0>();      // last step: only B outstanding
      RAWBAR;                       // all waves' B staged
    }
    const half_t* lA = smem + cur * 8192;
    const half_t* lB = smem + 16384;
#pragma unroll
    for (int kk = 0; kk < 2; ++kk) {
      half8 af[4], bfr[4];
      const int cg = kk * 4 + (lane >> 4);
#pragma unroll
      for (int i = 0; i < 4; ++i) {
        const int rA = wr * 64 + i * 16 + (lane & 15);
        af[i] = *(const half8*)&lA[rA * 64 + ((cg ^ (rA & 7)) << 3)];
      }
#pragma unroll
      for (int j = 0; j < 4; ++j) {
        const int rB = wc * 64 + j * 16 + (lane & 15);
        bfr[j] = *(const half8*)&lB[rB * 64 + ((cg ^ (rB & 7)) << 3)];
      }
      __builtin_amdgcn_s_setprio(1);
#pragma unroll
      for (int i = 0; i < 4; ++i)
#pragma unroll
        for (int j = 0; j < 4; ++j)
          acc[i][j] = __builtin_amdgcn_mfma_f32_16x16x32_f16(af[i], bfr[j],
                                                             acc[i][j], 0, 0, 0);
      __builtin_amdgcn_s_setprio(0);
    }
    RAWBAR;                         // all waves done reading lA[cur] and B
    if (ks < 7) {
      vmwait<0>();                  // A(ks+1) regs landed
      writeA(cur ^ 1);
      LGKM0;
      RAWBAR;                       // A(ks+1) visible to all waves
    }
    cur ^= 1;
  }

  // Epilogue: ep[n-of-tile (o)][m], pitch 132, dual-layout wide stores.
  constexpr int PIT = 132;
  half_t* ep = smem;
#pragma unroll
  for (int j = 0; j < 4; ++j) {
    const int nl = wc * 64 + j * 16 + (lane & 15);
    const float bv = bias[tn * 128 + nl];
#pragma unroll
    for (int i = 0; i < 4; ++i) {
      const int ml = wr * 64 + i * 16 + ((lane >> 4) << 2);
      half4 h;
#pragma unroll
      for (int r = 0; r < 4; ++r) h[r] = (half_t)(acc[i][j][r] + bv);
      *(half4*)&ep[nl * PIT + ml] = h;
    }
  }
  __syncthreads();
  { // Yf row-major (m, o-contig)
#pragma unroll
    for (int s = 0; s < 8; ++s) {
      const int q = tid + 256 * s;
      const int m = q & 127, cc8 = q >> 7;
      half8 v;
#pragma unroll
      for (int e = 0; e < 8; ++e) v[e] = ep[(cc8 * 8 + e) * PIT + m];
      *(half8*)&Co[(row0 + m) * CC + tn * 128 + cc8 * 8] = v;
    }
  }
  { // ycn (B, o, 4096)
#pragma unroll
    for (int s = 0; s < 8; ++s) {
      const int q = tid + 256 * s;
      const int mc = q & 15, cl = q >> 4;
      half8 v = *(const half8*)&ep[cl * PIT + mc * 8];
      *(half8*)&CoT[(b * CC + tn * 128 + cl) * CN + n0 + mc * 8] = v;
    }
  }
}

// ---------------------------------------------------------------------------
// Generic fp16 GEMM, A@B^T form (dbuf counted-vmcnt pipeline + swizzle).
// MODE bit0: +bias; bit1: relu; bit2: plain fp32 partial store into Cacc at
// split offset (blockIdx.y) — no atomics, regions disjoint.
// EPI bit0: LDS epilogue row-major. EPI bit1: transposed (B, Nn, 4096).
// STATS (requires EPI&2): fused per-channel sum/sumsq atomics into stats[].
template <int BM, int BN, int MODE, int EPI, bool SWZ, bool STATS>
__global__ __launch_bounds__(256) void gemm_abt(
    const half_t* __restrict__ A, const half_t* __restrict__ Bm,
    half_t* __restrict__ Co, half_t* __restrict__ CoT,
    float* __restrict__ Cacc, const float* __restrict__ bias,
    float* __restrict__ stats,
    int M, int Nn, int Kk, int ksplit, long sA, long sB, long sC)
{
  constexpr int FM = BM / 32, FN = BN / 32;
  constexpr int HB = (BM + BN) * 64;
  constexpr int LCNT = (BM / 8) / 4 + (BN / 8) / 4;
  constexpr int STG = 2 * HB;
  constexpr int EPS = (EPI != 0) ? BN * (BM + 4) : 0;
  constexpr int TOT = STG > EPS ? STG : EPS;
  __shared__ __align__(16) half_t smem[TOT];

  const int tid = threadIdx.x, wid = tid >> 6, lane = tid & 63;
  int bid = blockIdx.x;
  if constexpr (SWZ) bid = swz8(bid, gridDim.x);
  const int tilesN = Nn / BN;
  const int tm = bid / tilesN, tn = bid % tilesN;
  const long bz = blockIdx.z;
  const half_t* Ab = A + bz * sA + (long)tm * BM * Kk;
  const half_t* Bb = Bm + bz * sB + (long)tn * BN * Kk;
  const int ksteps = Kk >> 6;
  const int per = ksteps / ksplit;
  const int ks0 = blockIdx.y * per, ks1 = ks0 + per;
  const int wr = wid >> 1, wc = wid & 1;

  const int r8 = lane >> 3;
  const int gcs = ((lane & 7) ^ r8) * 8;

  auto stage = [&](int ks, int buf) {
    half_t* dA = smem + buf * HB;
    half_t* dB = dA + BM * 64;
    const half_t* ga = Ab + (long)ks * 64;
#pragma unroll
    for (int c = wid; c < BM / 8; c += 4)
      GLD_LDS(ga + (long)(c * 8 + r8) * Kk + gcs, &dA[c * 512]);
    const half_t* gb = Bb + (long)ks * 64;
#pragma unroll
    for (int c = wid; c < BN / 8; c += 4)
      GLD_LDS(gb + (long)(c * 8 + r8) * Kk + gcs, &dB[c * 512]);
  };

  f32x4 acc[FM][FN];
#pragma unroll
  for (int i = 0; i < FM; ++i)
#pragma unroll
    for (int j = 0; j < FN; ++j) acc[i][j] = f32x4{0.f, 0.f, 0.f, 0.f};

  stage(ks0, 0);
  if (ks0 + 1 < ks1) { stage(ks0 + 1, 1); vmwait<LCNT>(); }
  else               { vmwait<0>(); }
  RAWBAR;

  int cur = 0;
  for (int ks = ks0; ks < ks1; ++ks) {
    const half_t* lA = smem + cur * HB;
    const half_t* lB = lA + BM * 64;
#pragma unroll
    for (int kk = 0; kk < 2; ++kk) {
      half8 af[FM], bfr[FN];
      const int cg = kk * 4 + (lane >> 4);
#pragma unroll
      for (int i = 0; i < FM; ++i) {
        const int rA = wr * (BM / 2) + i * 16 + (lane & 15);
        af[i] = *(const half8*)&lA[rA * 64 + ((cg ^ (rA & 7)) << 3)];
      }
#pragma unroll
      for (int j = 0; j < FN; ++j) {
        const int rB = wc * (BN / 2) + j * 16 + (lane & 15);
        bfr[j] = *(const half8*)&lB[rB * 64 + ((cg ^ (rB & 7)) << 3)];
      }
      __builtin_amdgcn_s_setprio(1);
#pragma unroll
      for (int i = 0; i < FM; ++i)
#pragma unroll
        for (int j = 0; j < FN; ++j)
          acc[i][j] = __builtin_amdgcn_mfma_f32_16x16x32_f16(af[i], bfr[j],
                                                             acc[i][j], 0, 0, 0);
      __builtin_amdgcn_s_setprio(0);
    }
    RAWBAR;
    const bool more = (ks + 2 < ks1);
    if (more) { stage(ks + 2, cur); vmwait<LCNT>(); }
    else      { vmwait<0>(); }
    RAWBAR;
    cur ^= 1;
  }

  if constexpr (EPI != 0) {
    static_assert(BM == 128 && BN == 128, "LDS epilogue assumes 128x128");
    constexpr int PIT = BM + 4;
    half_t* ep = smem;
#pragma unroll
    for (int j = 0; j < FN; ++j) {
      const int nl = wc * 64 + j * 16 + (lane & 15);
      float bv = 0.f;
      if constexpr (MODE & 1) bv = bias[tn * BN + nl];
      float s1 = 0.f, s2 = 0.f;
#pragma unroll
      for (int i = 0; i < FM; ++i) {
        const int ml = wr * 64 + i * 16 + ((lane >> 4) << 2);
        half4 h;
#pragma unroll
        for (int r = 0; r < 4; ++r) {
          float v = acc[i][j][r] + bv;
          if constexpr (MODE & 2) v = fmaxf(v, 0.f);
          if constexpr (STATS) { s1 += v; s2 += v * v; }
          h[r] = (half_t)v;
        }
        *(half4*)&ep[nl * PIT + ml] = h;
      }
      if constexpr (STATS) {     // reduce 64 m-rows this wave holds (col nl)
        s1 += __shfl_xor(s1, 16); s1 += __shfl_xor(s1, 32);
        s2 += __shfl_xor(s2, 16); s2 += __shfl_xor(s2, 32);
        if (lane < 16) {
          const int ch = tn * BN + nl;
          atomicAdd(&stats[ch], s1);
          atomicAdd(&stats[CC + ch], s2);
        }
      }
    }
    __syncthreads();
    const long rowbase = (long)tm * BM;
    if constexpr (EPI & 1) {
#pragma unroll
      for (int s = 0; s < 8; ++s) {
        const int q = tid + 256 * s;
        const int m = q & 127, cc8 = q >> 7;
        half8 v;
#pragma unroll
        for (int e = 0; e < 8; ++e) v[e] = ep[(cc8 * 8 + e) * PIT + m];
        *(half8*)&Co[bz * sC + (rowbase + m) * Nn + tn * BN + cc8 * 8] = v;
      }
    }
    if constexpr (EPI & 2) {
      const long b = rowbase >> 12, nbase = rowbase & 4095;
#pragma unroll
      for (int s = 0; s < 8; ++s) {
        const int q = tid + 256 * s;
        const int mc = q & 15, cl = q >> 4;
        half8 v = *(const half8*)&ep[cl * PIT + mc * 8];
        *(half8*)&CoT[(b * Nn + tn * BN + cl) * 4096 + nbase + mc * 8] = v;
      }
    }
  } else {
#pragma unroll
    for (int j = 0; j < FN; ++j) {
      const int n = tn * BN + wc * (BN / 2) + j * 16 + (lane & 15);
      float bv = 0.f;
      if constexpr (MODE & 1) bv = bias[n];
#pragma unroll
      for (int i = 0; i < FM; ++i) {
        const int mbase = tm * BM + wr * (BM / 2) + i * 16 + ((lane >> 4) << 2);
#pragma unroll
        for (int r = 0; r < 4; ++r) {
          if constexpr ((MODE & 4) != 0) {   // per-split plain partial store
            const long idx = bz * sC + (long)blockIdx.y * ((long)BM * Nn) +
                             (long)(mbase + r) * Nn + n;
            Cacc[idx] = acc[i][j][r];
          } else {
            const long idx = bz * sC + (long)(mbase + r) * Nn + n;
            float v = acc[i][j][r] + bv;
            if constexpr ((MODE & 2) != 0) v = fmaxf(v, 0.f);
            Co[idx] = (half_t)v;
          }
        }
      }
    }
  }
}

// ---------------------------------------------------------------------------
// K3 (v11 verbatim): S = Yf @ muT^T, in-register rowwise softmax, writes zT
// always, z when zp != nullptr (final iter). Dbuf counted-vmcnt staging.
__global__ __launch_bounds__(256) void s_softmax(
    const half_t* __restrict__ Yf, const half_t* __restrict__ muT,
    half_t* __restrict__ zp, half_t* __restrict__ zT)
{
  constexpr int HB = (128 + 64) * 64;     // halfs per staging buffer
  __shared__ __align__(16) union {
    half_t st[2 * HB];                    // 48 KiB staging (dbuf)
    half_t zh[128 * 68];                  // epilogue z tile
  } sm;
  const int tid = threadIdx.x, wid = tid >> 6, lane = tid & 63;
  const int tm = blockIdx.x;
  const long bz = blockIdx.z;
  const half_t* Ab = Yf + bz * (long)CN * CC + (long)tm * 128 * CC;
  const half_t* Bb = muT + bz * (long)CKK * CC;

  const int r8 = lane >> 3;
  const int gcs = ((lane & 7) ^ r8) * 8;

  auto stage = [&](int ks, int buf) {
    half_t* dA = sm.st + buf * HB;
    half_t* dB = dA + 128 * 64;
    const half_t* ga = Ab + (long)ks * 64;
#pragma unroll
    for (int c = wid; c < 16; c += 4)
      GLD_LDS(ga + (long)(c * 8 + r8) * CC + gcs, &dA[c * 512]);
    const half_t* gb = Bb + (long)ks * 64;
#pragma unroll
    for (int c = wid; c < 8; c += 4)
      GLD_LDS(gb + (long)(c * 8 + r8) * CC + gcs, &dB[c * 512]);
  };

  f32x4 acc[2][4];
#pragma unroll
  for (int i = 0; i < 2; ++i)
#pragma unroll
    for (int j = 0; j < 4; ++j) acc[i][j] = f32x4{0.f, 0.f, 0.f, 0.f};

  stage(0, 0);
  stage(1, 1);
  vmwait<6>();
  RAWBAR;
  int cur = 0;
  for (int ks = 0; ks < 8; ++ks) {   // Kk = 512
    const half_t* lA = sm.st + cur * HB;
    const half_t* lB = lA + 128 * 64;
#pragma unroll
    for (int kk = 0; kk < 2; ++kk) {
      half8 af[2], bfr[4];
      const int cg = kk * 4 + (lane >> 4);
#pragma unroll
      for (int i = 0; i < 2; ++i) {
        const int rA = wid * 32 + i * 16 + (lane & 15);
        af[i] = *(const half8*)&lA[rA * 64 + ((cg ^ (rA & 7)) << 3)];
      }
#pragma unroll
      for (int j = 0; j < 4; ++j) {
        const int rB = j * 16 + (lane & 15);
        bfr[j] = *(const half8*)&lB[rB * 64 + ((cg ^ (rB & 7)) << 3)];
      }
      __builtin_amdgcn_s_setprio(1);
#pragma unroll
      for (int i = 0; i < 2; ++i)
#pragma unroll
        for (int j = 0; j < 4; ++j)
          acc[i][j] = __builtin_amdgcn_mfma_f32_16x16x32_f16(af[i], bfr[j],
                                                             acc[i][j], 0, 0, 0);
      __builtin_amdgcn_s_setprio(0);
    }
    RAWBAR;
    const bool more = (ks + 2 < 8);
    if (more) { stage(ks + 2, cur); vmwait<6>(); }
    else      { vmwait<0>(); }
    RAWBAR;
    cur ^= 1;
  }

  // In-register softmax over 64 cols per row.
#pragma unroll
  for (int i = 0; i < 2; ++i)
#pragma unroll
    for (int r = 0; r < 4; ++r) {
      float mx = fmaxf(fmaxf(acc[i][0][r], acc[i][1][r]),
                       fmaxf(acc[i][2][r], acc[i][3][r]));
#pragma unroll
      for (int m = 1; m < 16; m <<= 1) mx = fmaxf(mx, __shfl_xor(mx, m));
      float p[4], s = 0.f;
#pragma unroll
      for (int j = 0; j < 4; ++j) { p[j] = __expf(acc[i][j][r] - mx); s += p[j]; }
#pragma unroll
      for (int m = 1; m < 16; m <<= 1) s += __shfl_xor(s, m);
      const float inv = 1.f / s;
#pragma unroll
      for (int j = 0; j < 4; ++j) acc[i][j][r] = p[j] * inv;
    }

#pragma unroll
  for (int i = 0; i < 2; ++i)
#pragma unroll
    for (int j = 0; j < 4; ++j)
#pragma unroll
      for (int r = 0; r < 4; ++r) {
        const int row = wid * 32 + i * 16 + ((lane >> 4) << 2) + r;
        const int col = j * 16 + (lane & 15);
        sm.zh[row * 68 + col] = (half_t)acc[i][j][r];
      }
  __syncthreads();
  if (zp) { // z (N,K): rows n, contiguous k  (final iter only)
    const int nl = tid >> 1, seg = tid & 1;
    const long base = bz * (long)CN * CKK + (long)(tm * 128 + nl) * CKK + seg * 32;
#pragma unroll
    for (int g = 0; g < 4; ++g) {
      half8 v;
#pragma unroll
      for (int e = 0; e < 8; ++e) v[e] = sm.zh[nl * 68 + seg * 32 + g * 8 + e];
      *(half8*)&zp[base + g * 8] = v;
    }
  }
  { // zT (K,N): rows k, contiguous n
    const int k = tid >> 2, seg = tid & 3;
    const long base = bz * (long)CKK * CN + (long)k * CN + tm * 128 + seg * 32;
#pragma unroll
    for (int g = 0; g < 4; ++g) {
      half8 v;
#pragma unroll
      for (int e = 0; e < 8; ++e) v[e] = sm.zh[(seg * 32 + g * 8 + e) * 68 + k];
      *(half8*)&zT[base + g * 8] = v;
    }
  }
}

// ---------------------------------------------------------------------------
// mu = R / max(||R||_c, 1e-12) per (b,k), R = sum of 4 split partials.
// Writes muT (K,C) and mu_ck (C,K).
__global__ __launch_bounds__(64) void mu_norm(
    const float* __restrict__ acc, half_t* __restrict__ muT, half_t* __restrict__ muck)
{
  const int bk = blockIdx.x;           // b*64 + k
  const int b = bk >> 6, k = bk & 63;
  const float* base = acc + ((long)b * 4 * CKK + k) * CC;   // split stride K*C
  const int t = threadIdx.x;
  float v[8]; float s = 0.f;
#pragma unroll
  for (int e = 0; e < 8; ++e) {
    float a = base[t * 8 + e] + base[CKK * CC + t * 8 + e] +
              base[2 * CKK * CC + t * 8 + e] + base[3 * CKK * CC + t * 8 + e];
    v[e] = a; s += a * a;
  }
#pragma unroll
  for (int m = 1; m < 64; m <<= 1) s += __shfl_xor(s, m);
  const float inv = 1.f / fmaxf(sqrtf(s), 1e-12f);
  half8 o;
#pragma unroll
  for (int e = 0; e < 8; ++e) o[e] = (half_t)(v[e] * inv);
  *(half8*)&muT[(long)bk * CC + t * 8] = o;
  half_t* mc = muck + (long)b * CC * CKK;
#pragma unroll
  for (int e = 0; e < 8; ++e) mc[(long)(t * 8 + e) * CKK + k] = o[e];
}

// ---------------------------------------------------------------------------
// out(B,C,N) = relu( BN(hcn) + x ); BN params computed inline per thread.
__global__ __launch_bounds__(256) void bn_final3(
    const half_t* __restrict__ hcn, const float* __restrict__ x,
    const float* __restrict__ stats,
    const float* __restrict__ gamma, const float* __restrict__ beta,
    float* __restrict__ out)
{
  const long i8 = (long)blockIdx.x * 256 + threadIdx.x;   // 8-elem chunk id
  const int c = (int)((i8 >> 9) & 511);
  const float cnt = 1.f / 65536.f;
  const float mean = stats[c] * cnt;
  const float var = stats[CC + c] * cnt - mean * mean;
  const float sc = gamma[c] * rsqrtf(var + 1e-5f);
  const float sh = beta[c] - mean * sc;
  half8 h = *(const half8*)&hcn[i8 * 8];
  f32x4 x0 = *(const f32x4*)&x[i8 * 8];
  f32x4 x1 = *(const f32x4*)&x[i8 * 8 + 4];
  f32x4 o0, o1;
#pragma unroll
  for (int e = 0; e < 4; ++e) o0[e] = fmaxf((float)h[e] * sc + sh + x0[e], 0.f);
#pragma unroll
  for (int e = 0; e < 4; ++e) o1[e] = fmaxf((float)h[4 + e] * sc + sh + x1[e], 0.f);
  *(f32x4*)&out[i8 * 8] = o0;
  *(f32x4*)&out[i8 * 8 + 4] = o1;
}

// ---------------------------------------------------------------------------
extern "C" void kernel_launch(void* const* d_in, const int* in_sizes, int n_in,
                              void* d_out, int out_size, void* d_ws, size_t ws_size,
                              hipStream_t stream)
{
  const float* x      = (const float*)d_in[0];
  const float* mu     = (const float*)d_in[1];
  const float* stem_w = (const float*)d_in[2];
  const float* stem_b = (const float*)d_in[3];
  const float* head_w = (const float*)d_in[4];
  const float* head_b = (const float*)d_in[5];
  const float* bn_g   = (const float*)d_in[6];
  const float* bn_b   = (const float*)d_in[7];
  float* out = (float*)d_out;

  const size_t NEED = 214ull << 20;
  if (ws_size < NEED) {
    hipMemsetAsync(d_out, 0, (size_t)out_size * 4, stream);
    return;
  }
  char* ws = (char*)d_ws;
  const long MB = 1 << 20;
  half_t* y2f  = (half_t*)(ws);              // 64 MiB; during EM loop reused:
  float* muacc = (float*)(ws);               //   8 MiB (b,4,K,C) fp32 partials
  half_t* Yf   = (half_t*)(ws + 64 * MB);    // 64 MiB ; reused as hcn
  half_t* ycn  = (half_t*)(ws + 128 * MB);   // 64 MiB
  half_t* z    = (half_t*)(ws + 192 * MB);   // 8 MiB
  half_t* zT   = (half_t*)(ws + 200 * MB);   // 8 MiB
  half_t* muT  = (half_t*)(ws + 208 * MB);   // 1 MiB
  half_t* muck = (half_t*)(ws + 209 * MB);   // 1 MiB
  half_t* swh  = (half_t*)(ws + 212 * MB);
  half_t* hwh  = (half_t*)(ws + 212 * MB + 512 * 1024);
  float* stats = (float*)(ws + 213 * MB);
  half_t* hcn = Yf;    // Yf dead after final softmax

  prep<<<1024, 256, 0, stream>>>(stem_w, head_w, mu, swh, hwh, muT, muck, stats);
  // stem (fused x-transpose, 48 KB LDS): Yf (B*N,C) + ycn (B,C,N)
  gemm_stem<true><<<2048, 256, 0, stream>>>(x, swh, stem_b, Yf, ycn);

  for (int it = 0; it < 3; ++it) {
    s_softmax<<<dim3(32, 1, 16), 256, 0, stream>>>(
        Yf, muT, (it == 2) ? z : nullptr, zT);
    // mu partials (K,C) per split = zT @ ycn^T (4 splits, plain stores)
    gemm_abt<64, 128, 4, 0, false, false><<<dim3(4, 4, 16), 256, 0, stream>>>(
        zT, ycn, nullptr, nullptr, muacc, nullptr, nullptr, CKK, CC, CN, 4,
        (long)CKK * CN, (long)CC * CN, (long)4 * CKK * CC);
    mu_norm<<<CB * CKK, 64, 0, stream>>>(muacc, muT, muck);
  }
  // y2f (B,N,C) = relu(z @ mu_ck^T)
  gemm_abt<128, 128, 2, 1, true, false><<<dim3(128, 1, 16), 256, 0, stream>>>(
      z, muck, y2f, nullptr, nullptr, nullptr, nullptr, CN, CC, CKK, 1,
      (long)CN * CKK, (long)CC * CKK, (long)CN * CC);
  // head: hcn (B,C,N) = (y2f @ head_w^T + head_b), BN stats fused in epilogue
  gemm_abt<128, 128, 1, 2, true, true><<<dim3(2048, 1, 1), 256, 0, stream>>>(
      y2f, hwh, nullptr, hcn, nullptr, head_b, stats, (int)MALL, CC, CC, 1, 0, 0, 0);

  // out = relu(BN(hcn) + x), BN params inline from stats
  bn_final3<<<16384, 256, 0, stream>>>(hcn, x, stats, bn_g, bn_b, out);
}

// Round 17
// 375.053 us; speedup vs baseline: 1.0636x; 1.0143x over previous
//
#include <hip/hip_runtime.h>

// EMAttention2d on MI355X — v17: v16's 512-thread stem with the wave-tile math
// FIXED (acc[4][2]: each m-wave covers 64 rows = 4 fragments; v16's acc[2][2]
// left rows 32-63/96-127 uncomputed). Everything else v15-frozen.
// B=16, C=512, N=4096, K=64, 3 EM iters.
// mu_b = colnorm_c(yf^T @ z)  (zn normalization cancels under column L2 norm).

typedef _Float16 half_t;
typedef _Float16 half4 __attribute__((ext_vector_type(4)));
typedef _Float16 half8 __attribute__((ext_vector_type(8)));
typedef float f32x4 __attribute__((ext_vector_type(4)));

#define GLD_LDS(gp, lp) __builtin_amdgcn_global_load_lds( \
    (const __attribute__((address_space(1))) void*)(gp),  \
    (__attribute__((address_space(3))) void*)(lp), 16, 0, 0)

#define SBAR __builtin_amdgcn_sched_barrier(0)
#define RAWBAR do { SBAR; __builtin_amdgcn_s_barrier(); SBAR; } while (0)
#define LGKM0 do { asm volatile("s_waitcnt lgkmcnt(0)" ::: "memory"); SBAR; } while (0)

template <int L> __device__ __forceinline__ void vmwait() {
  if constexpr (L == 32) asm volatile("s_waitcnt vmcnt(32)" ::: "memory");
  else if constexpr (L == 16) asm volatile("s_waitcnt vmcnt(16)" ::: "memory");
  else if constexpr (L == 8) asm volatile("s_waitcnt vmcnt(8)" ::: "memory");
  else if constexpr (L == 6) asm volatile("s_waitcnt vmcnt(6)" ::: "memory");
  else if constexpr (L == 4) asm volatile("s_waitcnt vmcnt(4)" ::: "memory");
  else asm volatile("s_waitcnt vmcnt(0)" ::: "memory");
}

constexpr int CB = 16;       // batch
constexpr int CC = 512;      // channels
constexpr int CN = 4096;     // H*W
constexpr int CKK = 64;      // codebook size K
constexpr long MALL = (long)CB * CN;   // 65536

__device__ inline int swz8(int bid, int n) {   // bijective (n % 8 == 0)
  return (bid & 7) * (n >> 3) + (bid >> 3);
}

// ---------------------------------------------------------------------------
// K0: convert weights to fp16; init per-batch muT (K,C) and mu_ck (C,K);
// zero the BN stats accumulator.
__global__ __launch_bounds__(256) void prep(
    const float* __restrict__ stem_w, const float* __restrict__ head_w,
    const float* __restrict__ mu,
    half_t* __restrict__ swh, half_t* __restrict__ hwh,
    half_t* __restrict__ muT, half_t* __restrict__ muck,
    float* __restrict__ stats)
{
  int i = blockIdx.x * 256 + threadIdx.x;   // grid covers C*C = 262144
  swh[i] = (half_t)stem_w[i];
  hwh[i] = (half_t)head_w[i];
  if (i < CC * CKK) {
    int c = i >> 6, k = i & 63;
    half_t v = (half_t)mu[i];               // mu is (C,K) row-major
    for (int b = 0; b < CB; ++b) {
      muT[(long)b * CKK * CC + (long)k * CC + c] = v;
      muck[(long)b * CC * CKK + i] = v;
    }
  }
  if (blockIdx.x < 4) {                     // zero stats[1024]
    stats[blockIdx.x * 256 + threadIdx.x] = 0.f;
  }
}

// ---------------------------------------------------------------------------
// Stem GEMM fused with x-transpose, 512 threads / 8 waves (2m x 4n):
// per-wave 64m x 32n output (acc[4][2]), 16 MFMA per K-step.
// A-tile (64c x 128n) reg-staged (16 fp32 loads/thread, issued one step
// early), transposed+converted into swizzled LDS (dbuf 2x16 KB).
// B (weights, L2-resident) single-buffered 16 KB. LDS 48 KB.
template <bool SWZ>
__global__ __launch_bounds__(512) void gemm_stem(
    const float* __restrict__ X, const half_t* __restrict__ Bw,
    const float* __restrict__ bias,
    half_t* __restrict__ Co, half_t* __restrict__ CoT)
{
  // layout: A0 [0,8192) | A1 [8192,16384) | B [16384,24576)  (halfs)
  __shared__ __align__(16) half_t smem[24576];   // 48 KiB (epi reuses 33 KiB)
  const int tid = threadIdx.x, wid = tid >> 6, lane = tid & 63;
  int bid = blockIdx.x;
  if constexpr (SWZ) bid = swz8(bid, gridDim.x);
  const int tm = bid >> 2, tn = bid & 3;        // 512 m-tiles x 4 n-tiles
  const long row0 = (long)tm * 128;
  const long b = row0 >> 12;
  const int n0 = (int)(row0 & 4095);
  const float* Xb = X + b * ((long)CC * CN) + n0;
  const half_t* Bb = Bw + (long)tn * 128 * CC;
  const int wr = wid >> 2, wc = wid & 3;        // 2m x 4n waves

  const int an = tid & 127;                     // A: thread n
  const int ac0 = (tid >> 7) * 16;              // A: c-quarter 0/16/32/48
  const int r8 = lane >> 3;
  const int gcs = ((lane & 7) ^ r8) * 8;        // B pre-swizzled source col

  float va[16];
  auto issueA = [&](int ks) {
    const float* p = Xb + (long)(ks * 64 + ac0) * CN + an;
#pragma unroll
    for (int e = 0; e < 16; ++e) va[e] = p[(long)e * CN];
  };
  auto writeA = [&](int buf) {
    half_t* dA = smem + buf * 8192;
#pragma unroll
    for (int g = 0; g < 2; ++g) {
      half8 h;
#pragma unroll
      for (int e = 0; e < 8; ++e) h[e] = (half_t)va[g * 8 + e];
      const int chunk = (ac0 >> 3) + g;         // 0..7
      *(half8*)&dA[an * 64 + ((chunk ^ (an & 7)) << 3)] = h;
    }
  };
  auto stageB = [&](int ks) {                   // single buffer, 2 insts/wave
    half_t* dB = smem + 16384;
    const half_t* gb = Bb + (long)ks * 64;
#pragma unroll
    for (int c = wid; c < 16; c += 8)
      GLD_LDS(gb + (long)(c * 8 + r8) * CC + gcs, &dB[c * 512]);
  };

  f32x4 acc[4][2];
#pragma unroll
  for (int i = 0; i < 4; ++i)
#pragma unroll
    for (int j = 0; j < 2; ++j) acc[i][j] = f32x4{0.f, 0.f, 0.f, 0.f};

  // prologue: A(0) + B(0)
  issueA(0);
  stageB(0);
  vmwait<0>();
  writeA(0);
  LGKM0;
  RAWBAR;

  int cur = 0;
  for (int ks = 0; ks < 8; ++ks) {
    if (ks > 0) stageB(ks);         // B buf free since post-compute barrier
    if (ks < 7) issueA(ks + 1);     // HBM reg loads fly across compute
    if (ks > 0) {
      if (ks < 7) vmwait<16>();     // drain only B's 2; A's 16 stay in flight
      else        vmwait<0>();      // last step: only B outstanding
      RAWBAR;                       // all waves' B staged
    }
    const half_t* lA = smem + cur * 8192;
    const half_t* lB = smem + 16384;
#pragma unroll
    for (int kk = 0; kk < 2; ++kk) {
      half8 af[4], bfr[2];
      const int cg = kk * 4 + (lane >> 4);
#pragma unroll
      for (int i = 0; i < 4; ++i) {
        const int rA = wr * 64 + i * 16 + (lane & 15);
        af[i] = *(const half8*)&lA[rA * 64 + ((cg ^ (rA & 7)) << 3)];
      }
#pragma unroll
      for (int j = 0; j < 2; ++j) {
        const int rB = wc * 32 + j * 16 + (lane & 15);
        bfr[j] = *(const half8*)&lB[rB * 64 + ((cg ^ (rB & 7)) << 3)];
      }
      __builtin_amdgcn_s_setprio(1);
#pragma unroll
      for (int i = 0; i < 4; ++i)
#pragma unroll
        for (int j = 0; j < 2; ++j)
          acc[i][j] = __builtin_amdgcn_mfma_f32_16x16x32_f16(af[i], bfr[j],
                                                             acc[i][j], 0, 0, 0);
      __builtin_amdgcn_s_setprio(0);
    }
    RAWBAR;                         // all waves done reading lA[cur] and B
    if (ks < 7) {
      vmwait<0>();                  // A(ks+1) regs landed
      writeA(cur ^ 1);
      LGKM0;
      RAWBAR;                       // A(ks+1) visible to all waves
    }
    cur ^= 1;
  }

  // Epilogue: ep[n-of-tile (o)][m], pitch 132, dual-layout wide stores.
  constexpr int PIT = 132;
  half_t* ep = smem;
#pragma unroll
  for (int j = 0; j < 2; ++j) {
    const int nl = wc * 32 + j * 16 + (lane & 15);
    const float bv = bias[tn * 128 + nl];
#pragma unroll
    for (int i = 0; i < 4; ++i) {
      const int ml = wr * 64 + i * 16 + ((lane >> 4) << 2);
      half4 h;
#pragma unroll
      for (int r = 0; r < 4; ++r) h[r] = (half_t)(acc[i][j][r] + bv);
      *(half4*)&ep[nl * PIT + ml] = h;
    }
  }
  __syncthreads();
  { // Yf row-major (m, o-contig): 128 m x 16 chunks of half8 = 2048 stores
#pragma unroll
    for (int s = 0; s < 4; ++s) {
      const int q = tid + 512 * s;
      const int m = q & 127, cc8 = q >> 7;      // cc8 0..15
      half8 v;
#pragma unroll
      for (int e = 0; e < 8; ++e) v[e] = ep[(cc8 * 8 + e) * PIT + m];
      *(half8*)&Co[(row0 + m) * CC + tn * 128 + cc8 * 8] = v;
    }
  }
  { // ycn (B, o, 4096): 128 cl x 16 mc chunks of half8
#pragma unroll
    for (int s = 0; s < 4; ++s) {
      const int q = tid + 512 * s;
      const int mc = q & 15, cl = q >> 4;       // cl 0..127
      half8 v = *(const half8*)&ep[cl * PIT + mc * 8];
      *(half8*)&CoT[(b * CC + tn * 128 + cl) * CN + n0 + mc * 8] = v;
    }
  }
}

// ---------------------------------------------------------------------------
// Generic fp16 GEMM, A@B^T form (dbuf counted-vmcnt pipeline + swizzle).
// MODE bit0: +bias; bit1: relu; bit2: plain fp32 partial store into Cacc at
// split offset (blockIdx.y) — no atomics, regions disjoint.
// EPI bit0: LDS epilogue row-major. EPI bit1: transposed (B, Nn, 4096).
// STATS (requires EPI&2): fused per-channel sum/sumsq atomics into stats[].
template <int BM, int BN, int MODE, int EPI, bool SWZ, bool STATS>
__global__ __launch_bounds__(256) void gemm_abt(
    const half_t* __restrict__ A, const half_t* __restrict__ Bm,
    half_t* __restrict__ Co, half_t* __restrict__ CoT,
    float* __restrict__ Cacc, const float* __restrict__ bias,
    float* __restrict__ stats,
    int M, int Nn, int Kk, int ksplit, long sA, long sB, long sC)
{
  constexpr int FM = BM / 32, FN = BN / 32;
  constexpr int HB = (BM + BN) * 64;
  constexpr int LCNT = (BM / 8) / 4 + (BN / 8) / 4;
  constexpr int STG = 2 * HB;
  constexpr int EPS = (EPI != 0) ? BN * (BM + 4) : 0;
  constexpr int TOT = STG > EPS ? STG : EPS;
  __shared__ __align__(16) half_t smem[TOT];

  const int tid = threadIdx.x, wid = tid >> 6, lane = tid & 63;
  int bid = blockIdx.x;
  if constexpr (SWZ) bid = swz8(bid, gridDim.x);
  const int tilesN = Nn / BN;
  const int tm = bid / tilesN, tn = bid % tilesN;
  const long bz = blockIdx.z;
  const half_t* Ab = A + bz * sA + (long)tm * BM * Kk;
  const half_t* Bb = Bm + bz * sB + (long)tn * BN * Kk;
  const int ksteps = Kk >> 6;
  const int per = ksteps / ksplit;
  const int ks0 = blockIdx.y * per, ks1 = ks0 + per;
  const int wr = wid >> 1, wc = wid & 1;

  const int r8 = lane >> 3;
  const int gcs = ((lane & 7) ^ r8) * 8;

  auto stage = [&](int ks, int buf) {
    half_t* dA = smem + buf * HB;
    half_t* dB = dA + BM * 64;
    const half_t* ga = Ab + (long)ks * 64;
#pragma unroll
    for (int c = wid; c < BM / 8; c += 4)
      GLD_LDS(ga + (long)(c * 8 + r8) * Kk + gcs, &dA[c * 512]);
    const half_t* gb = Bb + (long)ks * 64;
#pragma unroll
    for (int c = wid; c < BN / 8; c += 4)
      GLD_LDS(gb + (long)(c * 8 + r8) * Kk + gcs, &dB[c * 512]);
  };

  f32x4 acc[FM][FN];
#pragma unroll
  for (int i = 0; i < FM; ++i)
#pragma unroll
    for (int j = 0; j < FN; ++j) acc[i][j] = f32x4{0.f, 0.f, 0.f, 0.f};

  stage(ks0, 0);
  if (ks0 + 1 < ks1) { stage(ks0 + 1, 1); vmwait<LCNT>(); }
  else               { vmwait<0>(); }
  RAWBAR;

  int cur = 0;
  for (int ks = ks0; ks < ks1; ++ks) {
    const half_t* lA = smem + cur * HB;
    const half_t* lB = lA + BM * 64;
#pragma unroll
    for (int kk = 0; kk < 2; ++kk) {
      half8 af[FM], bfr[FN];
      const int cg = kk * 4 + (lane >> 4);
#pragma unroll
      for (int i = 0; i < FM; ++i) {
        const int rA = wr * (BM / 2) + i * 16 + (lane & 15);
        af[i] = *(const half8*)&lA[rA * 64 + ((cg ^ (rA & 7)) << 3)];
      }
#pragma unroll
      for (int j = 0; j < FN; ++j) {
        const int rB = wc * (BN / 2) + j * 16 + (lane & 15);
        bfr[j] = *(const half8*)&lB[rB * 64 + ((cg ^ (rB & 7)) << 3)];
      }
      __builtin_amdgcn_s_setprio(1);
#pragma unroll
      for (int i = 0; i < FM; ++i)
#pragma unroll
        for (int j = 0; j < FN; ++j)
          acc[i][j] = __builtin_amdgcn_mfma_f32_16x16x32_f16(af[i], bfr[j],
                                                             acc[i][j], 0, 0, 0);
      __builtin_amdgcn_s_setprio(0);
    }
    RAWBAR;
    const bool more = (ks + 2 < ks1);
    if (more) { stage(ks + 2, cur); vmwait<LCNT>(); }
    else      { vmwait<0>(); }
    RAWBAR;
    cur ^= 1;
  }

  if constexpr (EPI != 0) {
    static_assert(BM == 128 && BN == 128, "LDS epilogue assumes 128x128");
    constexpr int PIT = BM + 4;
    half_t* ep = smem;
#pragma unroll
    for (int j = 0; j < FN; ++j) {
      const int nl = wc * 64 + j * 16 + (lane & 15);
      float bv = 0.f;
      if constexpr (MODE & 1) bv = bias[tn * BN + nl];
      float s1 = 0.f, s2 = 0.f;
#pragma unroll
      for (int i = 0; i < FM; ++i) {
        const int ml = wr * 64 + i * 16 + ((lane >> 4) << 2);
        half4 h;
#pragma unroll
        for (int r = 0; r < 4; ++r) {
          float v = acc[i][j][r] + bv;
          if constexpr (MODE & 2) v = fmaxf(v, 0.f);
          if constexpr (STATS) { s1 += v; s2 += v * v; }
          h[r] = (half_t)v;
        }
        *(half4*)&ep[nl * PIT + ml] = h;
      }
      if constexpr (STATS) {     // reduce 64 m-rows this wave holds (col nl)
        s1 += __shfl_xor(s1, 16); s1 += __shfl_xor(s1, 32);
        s2 += __shfl_xor(s2, 16); s2 += __shfl_xor(s2, 32);
        if (lane < 16) {
          const int ch = tn * BN + nl;
          atomicAdd(&stats[ch], s1);
          atomicAdd(&stats[CC + ch], s2);
        }
      }
    }
    __syncthreads();
    const long rowbase = (long)tm * BM;
    if constexpr (EPI & 1) {
#pragma unroll
      for (int s = 0; s < 8; ++s) {
        const int q = tid + 256 * s;
        const int m = q & 127, cc8 = q >> 7;
        half8 v;
#pragma unroll
        for (int e = 0; e < 8; ++e) v[e] = ep[(cc8 * 8 + e) * PIT + m];
        *(half8*)&Co[bz * sC + (rowbase + m) * Nn + tn * BN + cc8 * 8] = v;
      }
    }
    if constexpr (EPI & 2) {
      const long b = rowbase >> 12, nbase = rowbase & 4095;
#pragma unroll
      for (int s = 0; s < 8; ++s) {
        const int q = tid + 256 * s;
        const int mc = q & 15, cl = q >> 4;
        half8 v = *(const half8*)&ep[cl * PIT + mc * 8];
        *(half8*)&CoT[(b * Nn + tn * BN + cl) * 4096 + nbase + mc * 8] = v;
      }
    }
  } else {
#pragma unroll
    for (int j = 0; j < FN; ++j) {
      const int n = tn * BN + wc * (BN / 2) + j * 16 + (lane & 15);
      float bv = 0.f;
      if constexpr (MODE & 1) bv = bias[n];
#pragma unroll
      for (int i = 0; i < FM; ++i) {
        const int mbase = tm * BM + wr * (BM / 2) + i * 16 + ((lane >> 4) << 2);
#pragma unroll
        for (int r = 0; r < 4; ++r) {
          if constexpr ((MODE & 4) != 0) {   // per-split plain partial store
            const long idx = bz * sC + (long)blockIdx.y * ((long)BM * Nn) +
                             (long)(mbase + r) * Nn + n;
            Cacc[idx] = acc[i][j][r];
          } else {
            const long idx = bz * sC + (long)(mbase + r) * Nn + n;
            float v = acc[i][j][r] + bv;
            if constexpr ((MODE & 2) != 0) v = fmaxf(v, 0.f);
            Co[idx] = (half_t)v;
          }
        }
      }
    }
  }
}

// ---------------------------------------------------------------------------
// K3 (v11 verbatim): S = Yf @ muT^T, in-register rowwise softmax, writes zT
// always, z when zp != nullptr (final iter). Dbuf counted-vmcnt staging.
__global__ __launch_bounds__(256) void s_softmax(
    const half_t* __restrict__ Yf, const half_t* __restrict__ muT,
    half_t* __restrict__ zp, half_t* __restrict__ zT)
{
  constexpr int HB = (128 + 64) * 64;     // halfs per staging buffer
  __shared__ __align__(16) union {
    half_t st[2 * HB];                    // 48 KiB staging (dbuf)
    half_t zh[128 * 68];                  // epilogue z tile
  } sm;
  const int tid = threadIdx.x, wid = tid >> 6, lane = tid & 63;
  const int tm = blockIdx.x;
  const long bz = blockIdx.z;
  const half_t* Ab = Yf + bz * (long)CN * CC + (long)tm * 128 * CC;
  const half_t* Bb = muT + bz * (long)CKK * CC;

  const int r8 = lane >> 3;
  const int gcs = ((lane & 7) ^ r8) * 8;

  auto stage = [&](int ks, int buf) {
    half_t* dA = sm.st + buf * HB;
    half_t* dB = dA + 128 * 64;
    const half_t* ga = Ab + (long)ks * 64;
#pragma unroll
    for (int c = wid; c < 16; c += 4)
      GLD_LDS(ga + (long)(c * 8 + r8) * CC + gcs, &dA[c * 512]);
    const half_t* gb = Bb + (long)ks * 64;
#pragma unroll
    for (int c = wid; c < 8; c += 4)
      GLD_LDS(gb + (long)(c * 8 + r8) * CC + gcs, &dB[c * 512]);
  };

  f32x4 acc[2][4];
#pragma unroll
  for (int i = 0; i < 2; ++i)
#pragma unroll
    for (int j = 0; j < 4; ++j) acc[i][j] = f32x4{0.f, 0.f, 0.f, 0.f};

  stage(0, 0);
  stage(1, 1);
  vmwait<6>();
  RAWBAR;
  int cur = 0;
  for (int ks = 0; ks < 8; ++ks) {   // Kk = 512
    const half_t* lA = sm.st + cur * HB;
    const half_t* lB = lA + 128 * 64;
#pragma unroll
    for (int kk = 0; kk < 2; ++kk) {
      half8 af[2], bfr[4];
      const int cg = kk * 4 + (lane >> 4);
#pragma unroll
      for (int i = 0; i < 2; ++i) {
        const int rA = wid * 32 + i * 16 + (lane & 15);
        af[i] = *(const half8*)&lA[rA * 64 + ((cg ^ (rA & 7)) << 3)];
      }
#pragma unroll
      for (int j = 0; j < 4; ++j) {
        const int rB = j * 16 + (lane & 15);
        bfr[j] = *(const half8*)&lB[rB * 64 + ((cg ^ (rB & 7)) << 3)];
      }
      __builtin_amdgcn_s_setprio(1);
#pragma unroll
      for (int i = 0; i < 2; ++i)
#pragma unroll
        for (int j = 0; j < 4; ++j)
          acc[i][j] = __builtin_amdgcn_mfma_f32_16x16x32_f16(af[i], bfr[j],
                                                             acc[i][j], 0, 0, 0);
      __builtin_amdgcn_s_setprio(0);
    }
    RAWBAR;
    const bool more = (ks + 2 < 8);
    if (more) { stage(ks + 2, cur); vmwait<6>(); }
    else      { vmwait<0>(); }
    RAWBAR;
    cur ^= 1;
  }

  // In-register softmax over 64 cols per row.
#pragma unroll
  for (int i = 0; i < 2; ++i)
#pragma unroll
    for (int r = 0; r < 4; ++r) {
      float mx = fmaxf(fmaxf(acc[i][0][r], acc[i][1][r]),
                       fmaxf(acc[i][2][r], acc[i][3][r]));
#pragma unroll
      for (int m = 1; m < 16; m <<= 1) mx = fmaxf(mx, __shfl_xor(mx, m));
      float p[4], s = 0.f;
#pragma unroll
      for (int j = 0; j < 4; ++j) { p[j] = __expf(acc[i][j][r] - mx); s += p[j]; }
#pragma unroll
      for (int m = 1; m < 16; m <<= 1) s += __shfl_xor(s, m);
      const float inv = 1.f / s;
#pragma unroll
      for (int j = 0; j < 4; ++j) acc[i][j][r] = p[j] * inv;
    }

#pragma unroll
  for (int i = 0; i < 2; ++i)
#pragma unroll
    for (int j = 0; j < 4; ++j)
#pragma unroll
      for (int r = 0; r < 4; ++r) {
        const int row = wid * 32 + i * 16 + ((lane >> 4) << 2) + r;
        const int col = j * 16 + (lane & 15);
        sm.zh[row * 68 + col] = (half_t)acc[i][j][r];
      }
  __syncthreads();
  if (zp) { // z (N,K): rows n, contiguous k  (final iter only)
    const int nl = tid >> 1, seg = tid & 1;
    const long base = bz * (long)CN * CKK + (long)(tm * 128 + nl) * CKK + seg * 32;
#pragma unroll
    for (int g = 0; g < 4; ++g) {
      half8 v;
#pragma unroll
      for (int e = 0; e < 8; ++e) v[e] = sm.zh[nl * 68 + seg * 32 + g * 8 + e];
      *(half8*)&zp[base + g * 8] = v;
    }
  }
  { // zT (K,N): rows k, contiguous n
    const int k = tid >> 2, seg = tid & 3;
    const long base = bz * (long)CKK * CN + (long)k * CN + tm * 128 + seg * 32;
#pragma unroll
    for (int g = 0; g < 4; ++g) {
      half8 v;
#pragma unroll
      for (int e = 0; e < 8; ++e) v[e] = sm.zh[(seg * 32 + g * 8 + e) * 68 + k];
      *(half8*)&zT[base + g * 8] = v;
    }
  }
}

// ---------------------------------------------------------------------------
// mu = R / max(||R||_c, 1e-12) per (b,k), R = sum of 4 split partials.
// Writes muT (K,C) and mu_ck (C,K).
__global__ __launch_bounds__(64) void mu_norm(
    const float* __restrict__ acc, half_t* __restrict__ muT, half_t* __restrict__ muck)
{
  const int bk = blockIdx.x;           // b*64 + k
  const int b = bk >> 6, k = bk & 63;
  const float* base = acc + ((long)b * 4 * CKK + k) * CC;   // split stride K*C
  const int t = threadIdx.x;
  float v[8]; float s = 0.f;
#pragma unroll
  for (int e = 0; e < 8; ++e) {
    float a = base[t * 8 + e] + base[CKK * CC + t * 8 + e] +
              base[2 * CKK * CC + t * 8 + e] + base[3 * CKK * CC + t * 8 + e];
    v[e] = a; s += a * a;
  }
#pragma unroll
  for (int m = 1; m < 64; m <<= 1) s += __shfl_xor(s, m);
  const float inv = 1.f / fmaxf(sqrtf(s), 1e-12f);
  half8 o;
#pragma unroll
  for (int e = 0; e < 8; ++e) o[e] = (half_t)(v[e] * inv);
  *(half8*)&muT[(long)bk * CC + t * 8] = o;
  half_t* mc = muck + (long)b * CC * CKK;
#pragma unroll
  for (int e = 0; e < 8; ++e) mc[(long)(t * 8 + e) * CKK + k] = o[e];
}

// ---------------------------------------------------------------------------
// out(B,C,N) = relu( BN(hcn) + x ); BN params computed inline per thread.
__global__ __launch_bounds__(256) void bn_final3(
    const half_t* __restrict__ hcn, const float* __restrict__ x,
    const float* __restrict__ stats,
    const float* __restrict__ gamma, const float* __restrict__ beta,
    float* __restrict__ out)
{
  const long i8 = (long)blockIdx.x * 256 + threadIdx.x;   // 8-elem chunk id
  const int c = (int)((i8 >> 9) & 511);
  const float cnt = 1.f / 65536.f;
  const float mean = stats[c] * cnt;
  const float var = stats[CC + c] * cnt - mean * mean;
  const float sc = gamma[c] * rsqrtf(var + 1e-5f);
  const float sh = beta[c] - mean * sc;
  half8 h = *(const half8*)&hcn[i8 * 8];
  f32x4 x0 = *(const f32x4*)&x[i8 * 8];
  f32x4 x1 = *(const f32x4*)&x[i8 * 8 + 4];
  f32x4 o0, o1;
#pragma unroll
  for (int e = 0; e < 4; ++e) o0[e] = fmaxf((float)h[e] * sc + sh + x0[e], 0.f);
#pragma unroll
  for (int e = 0; e < 4; ++e) o1[e] = fmaxf((float)h[4 + e] * sc + sh + x1[e], 0.f);
  *(f32x4*)&out[i8 * 8] = o0;
  *(f32x4*)&out[i8 * 8 + 4] = o1;
}

// ---------------------------------------------------------------------------
extern "C" void kernel_launch(void* const* d_in, const int* in_sizes, int n_in,
                              void* d_out, int out_size, void* d_ws, size_t ws_size,
                              hipStream_t stream)
{
  const float* x      = (const float*)d_in[0];
  const float* mu     = (const float*)d_in[1];
  const float* stem_w = (const float*)d_in[2];
  const float* stem_b = (const float*)d_in[3];
  const float* head_w = (const float*)d_in[4];
  const float* head_b = (const float*)d_in[5];
  const float* bn_g   = (const float*)d_in[6];
  const float* bn_b   = (const float*)d_in[7];
  float* out = (float*)d_out;

  const size_t NEED = 214ull << 20;
  if (ws_size < NEED) {
    hipMemsetAsync(d_out, 0, (size_t)out_size * 4, stream);
    return;
  }
  char* ws = (char*)d_ws;
  const long MB = 1 << 20;
  half_t* y2f  = (half_t*)(ws);              // 64 MiB; during EM loop reused:
  float* muacc = (float*)(ws);               //   8 MiB (b,4,K,C) fp32 partials
  half_t* Yf   = (half_t*)(ws + 64 * MB);    // 64 MiB ; reused as hcn
  half_t* ycn  = (half_t*)(ws + 128 * MB);   // 64 MiB
  half_t* z    = (half_t*)(ws + 192 * MB);   // 8 MiB
  half_t* zT   = (half_t*)(ws + 200 * MB);   // 8 MiB
  half_t* muT  = (half_t*)(ws + 208 * MB);   // 1 MiB
  half_t* muck = (half_t*)(ws + 209 * MB);   // 1 MiB
  half_t* swh  = (half_t*)(ws + 212 * MB);
  half_t* hwh  = (half_t*)(ws + 212 * MB + 512 * 1024);
  float* stats = (float*)(ws + 213 * MB);
  half_t* hcn = Yf;    // Yf dead after final softmax

  prep<<<1024, 256, 0, stream>>>(stem_w, head_w, mu, swh, hwh, muT, muck, stats);
  // stem (fused x-transpose, 512 threads, 48 KB LDS): Yf + ycn
  gemm_stem<true><<<2048, 512, 0, stream>>>(x, swh, stem_b, Yf, ycn);

  for (int it = 0; it < 3; ++it) {
    s_softmax<<<dim3(32, 1, 16), 256, 0, stream>>>(
        Yf, muT, (it == 2) ? z : nullptr, zT);
    // mu partials (K,C) per split = zT @ ycn^T (4 splits, plain stores)
    gemm_abt<64, 128, 4, 0, false, false><<<dim3(4, 4, 16), 256, 0, stream>>>(
        zT, ycn, nullptr, nullptr, muacc, nullptr, nullptr, CKK, CC, CN, 4,
        (long)CKK * CN, (long)CC * CN, (long)4 * CKK * CC);
    mu_norm<<<CB * CKK, 64, 0, stream>>>(muacc, muT, muck);
  }
  // y2f (B,N,C) = relu(z @ mu_ck^T)
  gemm_abt<128, 128, 2, 1, true, false><<<dim3(128, 1, 16), 256, 0, stream>>>(
      z, muck, y2f, nullptr, nullptr, nullptr, nullptr, CN, CC, CKK, 1,
      (long)CN * CKK, (long)CC * CKK, (long)CN * CC);
  // head: hcn (B,C,N) = (y2f @ head_w^T + head_b), BN stats fused in epilogue
  gemm_abt<128, 128, 1, 2, true, true><<<dim3(2048, 1, 1), 256, 0, stream>>>(
      y2f, hwh, nullptr, hcn, nullptr, head_b, stats, (int)MALL, CC, CC, 1, 0, 0, 0);

  // out = relu(BN(hcn) + x), BN params inline from stats
  bn_final3<<<16384, 256, 0, stream>>>(hcn, x, stats, bn_g, bn_b, out);
}